// Round 6
// baseline (427.121 us; speedup 1.0000x reference)
//
#include <hip/hip_runtime.h>

#define BLK 256
#define SB_SHIFT 7          // 128 dst per bucket
#define NBMAX 576
#define CHUNK_E 4096

// ---------------- generic zero ----------------

__global__ void zero_kernel(int* __restrict__ p, int n) {
    int i = blockIdx.x * blockDim.x + threadIdx.x;
    if (i < n) p[i] = 0;
}

// ---------------- bucketed CSR build ----------------

struct BJobs {
    const int* src[3];
    const int* dst[3];
    int E[3];
    int Eoff[4];       // concat edge offsets per relation
    int nboff[4];      // concat bucket-id offsets per relation
    int ndst[3];
    int Roff[3];       // row_ptr concat offsets per relation
    int chunk_off[4];  // chunk-block offsets per relation
};

__launch_bounds__(BLK)
__global__ void bhist_kernel(BJobs J, int* __restrict__ gcnt, int NB) {
    __shared__ int lc[NBMAX];
    int tid = threadIdx.x;
    for (int i = tid; i < NB; i += BLK) lc[i] = 0;
    __syncthreads();
    int b = blockIdx.x, r = 0;
    while (b >= J.chunk_off[r + 1]) ++r;
    int e0 = (b - J.chunk_off[r]) * CHUNK_E;
    int e1 = min(e0 + CHUNK_E, J.E[r]);
    const int* __restrict__ dst = J.dst[r];
    int base = J.nboff[r];
    for (int e = e0 + tid; e < e1; e += BLK)
        atomicAdd(&lc[base + (dst[e] >> SB_SHIFT)], 1);
    __syncthreads();
    for (int i = tid; i < NB; i += BLK)
        if (lc[i]) atomicAdd(&gcnt[i], lc[i]);
}

// Block-wide exclusive scan (256 threads, 16 items/thread/chunk).
__device__ void scan_block(const int* __restrict__ cnt, int* __restrict__ row,
                           int* __restrict__ cur, int n) {
    __shared__ int wsum[4];
    __shared__ int s_carry;
    const int ITEMS = 16;
    const int CHUNK = BLK * ITEMS;
    int lane = threadIdx.x & 63;
    int wv = threadIdx.x >> 6;
    if (threadIdx.x == 0) s_carry = 0;
    __syncthreads();
    for (int base = 0; base < n; base += CHUNK) {
        int idx0 = base + threadIdx.x * ITEMS;
        int v[ITEMS];
        int tsum = 0;
#pragma unroll
        for (int j = 0; j < ITEMS; ++j) {
            int i = idx0 + j;
            v[j] = (i < n) ? cnt[i] : 0;
            tsum += v[j];
        }
        int incl = tsum;
#pragma unroll
        for (int off = 1; off < 64; off <<= 1) {
            int t = __shfl_up(incl, off);
            if (lane >= off) incl += t;
        }
        if (lane == 63) wsum[wv] = incl;
        __syncthreads();
        int carry = s_carry;
        int woff = 0;
        for (int w = 0; w < wv; ++w) woff += wsum[w];
        int excl = carry + woff + (incl - tsum);
#pragma unroll
        for (int j = 0; j < ITEMS; ++j) {
            int i = idx0 + j;
            if (i < n) { row[i] = excl; cur[i] = excl; }
            excl += v[j];
        }
        __syncthreads();
        if (threadIdx.x == 0) s_carry = carry + wsum[0] + wsum[1] + wsum[2] + wsum[3];
        __syncthreads();
    }
    if (threadIdx.x == 0) row[n] = s_carry;
}

__global__ void bscan_kernel(const int* __restrict__ gcnt, int* __restrict__ bbase,
                             int* __restrict__ bcur, int n) {
    scan_block(gcnt, bbase, bcur, n);
}

__launch_bounds__(BLK)
__global__ void bbin_kernel(BJobs J, int* __restrict__ bcur, int2* __restrict__ ebuf, int NB) {
    __shared__ int lc[NBMAX];
    __shared__ int res[NBMAX];
    __shared__ int cur[NBMAX];
    int tid = threadIdx.x;
    for (int i = tid; i < NB; i += BLK) { lc[i] = 0; cur[i] = 0; }
    __syncthreads();
    int b = blockIdx.x, r = 0;
    while (b >= J.chunk_off[r + 1]) ++r;
    int e0 = (b - J.chunk_off[r]) * CHUNK_E;
    int e1 = min(e0 + CHUNK_E, J.E[r]);
    const int* __restrict__ src = J.src[r];
    const int* __restrict__ dst = J.dst[r];
    int base = J.nboff[r];
    for (int e = e0 + tid; e < e1; e += BLK)
        atomicAdd(&lc[base + (dst[e] >> SB_SHIFT)], 1);
    __syncthreads();
    for (int i = tid; i < NB; i += BLK)
        if (lc[i]) res[i] = atomicAdd(&bcur[i], lc[i]);
    __syncthreads();
    for (int e = e0 + tid; e < e1; e += BLK) {
        int s = src[e], d = dst[e];
        int bk = base + (d >> SB_SHIFT);
        int l = atomicAdd(&cur[bk], 1);
        ebuf[res[bk] + l] = make_int2(s, d);
    }
}

// One block per bucket: per-dst count, 128-wide scan, write row_ptr, place edges.
__launch_bounds__(BLK)
__global__ void bplace_kernel(BJobs J, const int* __restrict__ bbase,
                              const int2* __restrict__ ebuf,
                              int* __restrict__ ccsr, int* __restrict__ rowcat) {
    __shared__ int cnt[128];
    __shared__ int off[128];
    __shared__ int cur[128];
    int tid = threadIdx.x;
    int bk = blockIdx.x, r = 0;
    while (bk >= J.nboff[r + 1]) ++r;
    int dst0 = (bk - J.nboff[r]) << SB_SHIFT;
    int nd = J.ndst[r] - dst0;
    if (nd > 128) nd = 128;
    int ebase = bbase[bk], eend = bbase[bk + 1];
    if (tid < 128) cnt[tid] = 0;
    __syncthreads();
    for (int e = ebase + tid; e < eend; e += BLK)
        atomicAdd(&cnt[ebuf[e].y - dst0], 1);
    __syncthreads();
    if (tid < 128) off[tid] = cnt[tid];
    __syncthreads();
    for (int st = 1; st < 128; st <<= 1) {
        int v = 0;
        if (tid < 128 && tid >= st) v = off[tid - st];
        __syncthreads();
        if (tid < 128) off[tid] += v;
        __syncthreads();
    }
    int Eo = J.Eoff[r];
    int* __restrict__ row = rowcat + J.Roff[r];
    if (tid < nd) {
        int ex = off[tid] - cnt[tid];           // exclusive within-bucket offset
        row[dst0 + tid] = ebase + ex - Eo;      // relation-relative
        cur[tid] = ex;
    }
    if (tid == 0 && dst0 + nd == J.ndst[r])
        row[J.ndst[r]] = bbase[J.nboff[r + 1]] - Eo;
    __syncthreads();
    for (int e = ebase + tid; e < eend; e += BLK) {
        int2 sd = ebuf[e];
        int l = atomicAdd(&cur[sd.y - dst0], 1);
        ccsr[ebase + l] = sd.x;
    }
}

// ---------------- Dense transform: y = x @ W^T (+ b) ----------------
// Lane = output channel h. W in LDS [dq][h] (conflict-free b128 reads, no
// Wreg pressure). x double-buffered in LDS, loads for half k+1 issued
// BEFORE the FMA block of half k (latency hidden). 8 nodes per half ->
// 8 independent accumulator chains.

struct TJobs {
    const float* x[6];
    const float* W[6];
    const float* b[6];
    float* y[6];
    int n[6];
    int boff[7];
};

__launch_bounds__(BLK)
__global__ void transform_kernel(TJobs J) {
    __shared__ float4 WT4[1024];           // [dq][h], 16KB
    __shared__ float4 xbuf[2][4][8][16];   // [buf][wave][nodeSub][quad], 16KB
    int b = blockIdx.x, j = 0;
    while (b >= J.boff[j + 1]) ++j;
    int n = J.n[j];
    const float4* __restrict__ x4 = (const float4*)J.x[j];
    const float4* __restrict__ W4 = (const float4*)J.W[j];
    const float* bb = J.b[j];
    float* __restrict__ y = J.y[j];
    int tid = threadIdx.x, lane = tid & 63, wv = tid >> 6;

    // stage W: wave wv handles dq = wv*4..wv*4+3; lanes = h -> conflict-free
#pragma unroll
    for (int t = 0; t < 4; ++t) {
        int dq = wv * 4 + t;
        WT4[dq * 64 + lane] = W4[lane * 16 + dq];   // W[h=lane][dq*4..+3]
    }
    __syncthreads();
    float bias = bb ? bb[lane] : 0.f;

    int base = (b - J.boff[j]) * 64 + wv * 16;   // this wave's 16 nodes
    int s0 = lane >> 4, q = lane & 15;           // lane's load slot

    float4 p0, p1;
    auto issue = [&](int it) {
        int na = base + it * 8 + s0;
        int nb_ = na + 4;
        p0 = make_float4(0.f, 0.f, 0.f, 0.f);
        p1 = make_float4(0.f, 0.f, 0.f, 0.f);
        if (na < n) p0 = x4[(size_t)na * 16 + q];
        if (nb_ < n) p1 = x4[(size_t)nb_ * 16 + q];
    };
    auto commit = [&](int bufi) {
        xbuf[bufi][wv][s0][q] = p0;
        xbuf[bufi][wv][s0 + 4][q] = p1;
    };
    auto compute = [&](int bufi, int it) {
        float o[8];
#pragma unroll
        for (int s = 0; s < 8; ++s) o[s] = bias;
#pragma unroll
        for (int dq = 0; dq < 16; ++dq) {
            float4 w = WT4[dq * 64 + lane];
#pragma unroll
            for (int s = 0; s < 8; ++s) {
                float4 m = xbuf[bufi][wv][s][dq];
                o[s] += w.x * m.x + w.y * m.y + w.z * m.z + w.w * m.w;
            }
        }
#pragma unroll
        for (int s = 0; s < 8; ++s) {
            int node = base + it * 8 + s;
            if (node < n) y[(size_t)node * 64 + lane] = o[s];
        }
    };

    issue(0);
    commit(0);       // prologue: stall on first half's loads
    issue(1);        // second half's loads in flight...
    compute(0, 0);   // ...hidden under this FMA block
    commit(1);
    compute(1, 1);
}

// ---------------- Gather-mean + add (RMW into out), 8-way unrolled ----------------

struct GJobs {
    const float* y[3];
    const int* row[3];
    const int* csr[3];
    float* out[3];
    int n[3];
    int boff[4];
    int relu;
};

__launch_bounds__(BLK)
__global__ void gather_kernel(GJobs J) {
    int b = blockIdx.x, j = 0;
    while (b >= J.boff[j + 1]) ++j;
    int lane = threadIdx.x & 63, wv = threadIdx.x >> 6;
    int node = (b - J.boff[j]) * 4 + wv;
    if (node >= J.n[j]) return;
    const int* __restrict__ row = J.row[j];
    const int* __restrict__ csr = J.csr[j];
    const float* __restrict__ y = J.y[j];
    float* __restrict__ out = J.out[j];

    int e0 = row[node], e1 = row[node + 1];
    float a0 = 0.f, a1 = 0.f, a2 = 0.f, a3 = 0.f;
    float a4 = 0.f, a5 = 0.f, a6 = 0.f, a7 = 0.f;
    int e = e0;
    for (; e + 8 <= e1; e += 8) {
        int s0 = csr[e + 0], s1 = csr[e + 1], s2 = csr[e + 2], s3 = csr[e + 3];
        int s4 = csr[e + 4], s5 = csr[e + 5], s6 = csr[e + 6], s7 = csr[e + 7];
        a0 += y[(size_t)s0 * 64 + lane];
        a1 += y[(size_t)s1 * 64 + lane];
        a2 += y[(size_t)s2 * 64 + lane];
        a3 += y[(size_t)s3 * 64 + lane];
        a4 += y[(size_t)s4 * 64 + lane];
        a5 += y[(size_t)s5 * 64 + lane];
        a6 += y[(size_t)s6 * 64 + lane];
        a7 += y[(size_t)s7 * 64 + lane];
    }
    for (; e < e1; ++e) a0 += y[(size_t)csr[e] * 64 + lane];
    int deg = e1 - e0;
    float m = ((a0 + a1) + (a2 + a3)) + ((a4 + a5) + (a6 + a7));
    m = deg ? m / (float)deg : 0.f;
    size_t oi = (size_t)node * 64 + lane;
    float o = m + out[oi];
    if (J.relu) o = fmaxf(o, 0.f);
    out[oi] = o;
}

// ---------------- Host ----------------

extern "C" void kernel_launch(void* const* d_in, const int* in_sizes, int n_in,
                              void* d_out, int out_size, void* d_ws, size_t ws_size,
                              hipStream_t stream) {
    const float* x_user    = (const float*)d_in[0];
    const float* x_problem = (const float*)d_in[1];
    const float* x_topic   = (const float*)d_in[2];
    const int* up_src = (const int*)d_in[3];
    const int* up_dst = (const int*)d_in[4];
    const int* pt_src = (const int*)d_in[5];
    const int* pt_dst = (const int*)d_in[6];
    const int* pu_src = (const int*)d_in[7];
    const int* pu_dst = (const int*)d_in[8];
    const float* W1_up_l = (const float*)d_in[9];
    const float* W1_up_r = (const float*)d_in[10];
    const float* W1_pt_l = (const float*)d_in[11];
    const float* W1_pt_r = (const float*)d_in[12];
    const float* W1_pu_l = (const float*)d_in[13];
    const float* W1_pu_r = (const float*)d_in[14];
    const float* W2_up_l = (const float*)d_in[15];
    const float* W2_up_r = (const float*)d_in[16];
    const float* W2_pt_l = (const float*)d_in[17];
    const float* W2_pt_r = (const float*)d_in[18];
    const float* W2_pu_l = (const float*)d_in[19];
    const float* W2_pu_r = (const float*)d_in[20];
    const float* b1_up = (const float*)d_in[21];
    const float* b1_pt = (const float*)d_in[22];
    const float* b1_pu = (const float*)d_in[23];
    const float* b2_up = (const float*)d_in[24];
    const float* b2_pt = (const float*)d_in[25];
    const float* b2_pu = (const float*)d_in[26];

    int n_user = in_sizes[0] / 64;
    int n_problem = in_sizes[1] / 64;
    int n_topic = in_sizes[2] / 64;
    int E_up = in_sizes[3];
    int E_pt = in_sizes[5];
    int E_pu = in_sizes[7];
    int E_tot = E_up + E_pt + E_pu;

    float* o_user = (float*)d_out;
    float* o_problem = o_user + (size_t)n_user * 64;
    float* o_topic = o_problem + (size_t)n_problem * 64;

    char* ws = (char*)d_ws;
    size_t off = 0;
    auto alloc = [&](size_t bytes) -> void* {
        void* p = ws + off;
        off += (bytes + 255) & ~(size_t)255;
        return p;
    };
    float* h_user    = (float*)alloc((size_t)n_user * 64 * 4);
    float* h_problem = (float*)alloc((size_t)n_problem * 64 * 4);
    float* h_topic   = (float*)alloc((size_t)n_topic * 64 * 4);
    // y buffers; the front of this region doubles as ebuf (int2 per edge) during CSR build
    float* y_up = (float*)alloc((size_t)n_user * 64 * 4);
    float* y_pt = (float*)alloc((size_t)n_problem * 64 * 4);
    float* y_pu = (float*)alloc((size_t)n_problem * 64 * 4);
    int2* ebuf = (int2*)y_up;  // 16.5MB needed, 23MB available before first transform

    auto cdiv = [](int a, int b) { return (a + b - 1) / b; };

    // buckets: relations ordered [up(dst=problem), pt(dst=topic), pu(dst=user)]
    int nb0 = cdiv(n_problem, 128), nb1 = cdiv(n_topic, 128), nb2 = cdiv(n_user, 128);
    int NB = nb0 + nb1 + nb2;

    int* gcnt  = (int*)alloc((size_t)(NB) * 4);
    int* bbase = (int*)alloc((size_t)(NB + 1) * 4);
    int* bcur  = (int*)alloc((size_t)(NB + 1) * 4);
    int* rowcat = (int*)alloc((size_t)(n_problem + n_topic + n_user + 3) * 4);
    int* ccsr  = (int*)alloc((size_t)E_tot * 4);

    BJobs B;
    B.src[0] = up_src; B.dst[0] = up_dst; B.E[0] = E_up;
    B.src[1] = pt_src; B.dst[1] = pt_dst; B.E[1] = E_pt;
    B.src[2] = pu_src; B.dst[2] = pu_dst; B.E[2] = E_pu;
    B.Eoff[0] = 0; B.Eoff[1] = E_up; B.Eoff[2] = E_up + E_pt; B.Eoff[3] = E_tot;
    B.nboff[0] = 0; B.nboff[1] = nb0; B.nboff[2] = nb0 + nb1; B.nboff[3] = NB;
    B.ndst[0] = n_problem; B.ndst[1] = n_topic; B.ndst[2] = n_user;
    B.Roff[0] = 0; B.Roff[1] = n_problem + 1; B.Roff[2] = n_problem + 1 + n_topic + 1;
    B.chunk_off[0] = 0;
    for (int r = 0; r < 3; ++r) B.chunk_off[r + 1] = B.chunk_off[r] + cdiv(B.E[r], CHUNK_E);

    const int* row_up = rowcat + B.Roff[0];
    const int* row_pt = rowcat + B.Roff[1];
    const int* row_pu = rowcat + B.Roff[2];
    const int* csr_up = ccsr + B.Eoff[0];
    const int* csr_pt = ccsr + B.Eoff[1];
    const int* csr_pu = ccsr + B.Eoff[2];

    zero_kernel<<<cdiv(NB, 256), 256, 0, stream>>>(gcnt, NB);
    bhist_kernel<<<B.chunk_off[3], BLK, 0, stream>>>(B, gcnt, NB);
    bscan_kernel<<<1, BLK, 0, stream>>>(gcnt, bbase, bcur, NB);
    bbin_kernel<<<B.chunk_off[3], BLK, 0, stream>>>(B, bcur, ebuf, NB);
    bplace_kernel<<<B.nboff[3], BLK, 0, stream>>>(B, bbase, ebuf, ccsr, rowcat);

    // ---- layer 1 ----
    {
        TJobs T;
        const float* xs[6] = {x_user, x_problem, x_problem, x_problem, x_topic, x_user};
        const float* Ws[6] = {W1_up_l, W1_pt_l, W1_pu_l, W1_up_r, W1_pt_r, W1_pu_r};
        const float* bs[6] = {nullptr, nullptr, nullptr, b1_up, b1_pt, b1_pu};
        float* ys[6] = {y_up, y_pt, y_pu, h_problem, h_topic, h_user};
        int ns[6] = {n_user, n_problem, n_problem, n_problem, n_topic, n_user};
        T.boff[0] = 0;
        for (int j = 0; j < 6; ++j) {
            T.x[j] = xs[j]; T.W[j] = Ws[j]; T.b[j] = bs[j]; T.y[j] = ys[j]; T.n[j] = ns[j];
            T.boff[j + 1] = T.boff[j] + cdiv(ns[j], 64);
        }
        transform_kernel<<<T.boff[6], BLK, 0, stream>>>(T);

        GJobs G;
        const float* gy[3] = {y_pu, y_up, y_pt};
        const int* gr[3] = {row_pu, row_up, row_pt};
        const int* gc[3] = {csr_pu, csr_up, csr_pt};
        float* go[3] = {h_user, h_problem, h_topic};
        int gn[3] = {n_user, n_problem, n_topic};
        G.boff[0] = 0;
        for (int j = 0; j < 3; ++j) {
            G.y[j] = gy[j]; G.row[j] = gr[j]; G.csr[j] = gc[j]; G.out[j] = go[j]; G.n[j] = gn[j];
            G.boff[j + 1] = G.boff[j] + cdiv(gn[j], 4);
        }
        G.relu = 1;
        gather_kernel<<<G.boff[3], BLK, 0, stream>>>(G);
    }

    // ---- layer 2 ----
    {
        TJobs T;
        const float* xs[6] = {h_user, h_problem, h_problem, h_problem, h_topic, h_user};
        const float* Ws[6] = {W2_up_l, W2_pt_l, W2_pu_l, W2_up_r, W2_pt_r, W2_pu_r};
        const float* bs[6] = {nullptr, nullptr, nullptr, b2_up, b2_pt, b2_pu};
        float* ys[6] = {y_up, y_pt, y_pu, o_problem, o_topic, o_user};
        int ns[6] = {n_user, n_problem, n_problem, n_problem, n_topic, n_user};
        T.boff[0] = 0;
        for (int j = 0; j < 6; ++j) {
            T.x[j] = xs[j]; T.W[j] = Ws[j]; T.b[j] = bs[j]; T.y[j] = ys[j]; T.n[j] = ns[j];
            T.boff[j + 1] = T.boff[j] + cdiv(ns[j], 64);
        }
        transform_kernel<<<T.boff[6], BLK, 0, stream>>>(T);

        GJobs G;
        const float* gy[3] = {y_pu, y_up, y_pt};
        const int* gr[3] = {row_pu, row_up, row_pt};
        const int* gc[3] = {csr_pu, csr_up, csr_pt};
        float* go[3] = {o_user, o_problem, o_topic};
        int gn[3] = {n_user, n_problem, n_topic};
        G.boff[0] = 0;
        for (int j = 0; j < 3; ++j) {
            G.y[j] = gy[j]; G.row[j] = gr[j]; G.csr[j] = gc[j]; G.out[j] = go[j]; G.n[j] = gn[j];
            G.boff[j + 1] = G.boff[j] + cdiv(gn[j], 4);
        }
        G.relu = 0;
        gather_kernel<<<G.boff[3], BLK, 0, stream>>>(G);
    }
}

// Round 7
// 397.643 us; speedup vs baseline: 1.0741x; 1.0741x over previous
//
#include <hip/hip_runtime.h>

#define BLK 256
#define SB_SHIFT 7          // 128 dst per bucket
#define NBMAX 576
#define CHUNK_E 4096
#define TNT 128             // nodes per transform block

// ---------------- generic zero ----------------

__global__ void zero_kernel(int* __restrict__ p, int n) {
    int i = blockIdx.x * blockDim.x + threadIdx.x;
    if (i < n) p[i] = 0;
}

// ---------------- bucketed CSR build ----------------

struct BJobs {
    const int* src[3];
    const int* dst[3];
    int E[3];
    int Eoff[4];       // concat edge offsets per relation
    int nboff[4];      // concat bucket-id offsets per relation
    int ndst[3];
    int Roff[3];       // row_ptr concat offsets per relation
    int chunk_off[4];  // chunk-block offsets per relation
};

__launch_bounds__(BLK)
__global__ void bhist_kernel(BJobs J, int* __restrict__ gcnt, int NB) {
    __shared__ int lc[NBMAX];
    int tid = threadIdx.x;
    for (int i = tid; i < NB; i += BLK) lc[i] = 0;
    __syncthreads();
    int b = blockIdx.x, r = 0;
    while (b >= J.chunk_off[r + 1]) ++r;
    int e0 = (b - J.chunk_off[r]) * CHUNK_E;
    int e1 = min(e0 + CHUNK_E, J.E[r]);
    const int* __restrict__ dst = J.dst[r];
    int base = J.nboff[r];
    for (int e = e0 + tid; e < e1; e += BLK)
        atomicAdd(&lc[base + (dst[e] >> SB_SHIFT)], 1);
    __syncthreads();
    for (int i = tid; i < NB; i += BLK)
        if (lc[i]) atomicAdd(&gcnt[i], lc[i]);
}

// Block-wide exclusive scan (256 threads, 16 items/thread/chunk).
__device__ void scan_block(const int* __restrict__ cnt, int* __restrict__ row,
                           int* __restrict__ cur, int n) {
    __shared__ int wsum[4];
    __shared__ int s_carry;
    const int ITEMS = 16;
    const int CHUNK = BLK * ITEMS;
    int lane = threadIdx.x & 63;
    int wv = threadIdx.x >> 6;
    if (threadIdx.x == 0) s_carry = 0;
    __syncthreads();
    for (int base = 0; base < n; base += CHUNK) {
        int idx0 = base + threadIdx.x * ITEMS;
        int v[ITEMS];
        int tsum = 0;
#pragma unroll
        for (int j = 0; j < ITEMS; ++j) {
            int i = idx0 + j;
            v[j] = (i < n) ? cnt[i] : 0;
            tsum += v[j];
        }
        int incl = tsum;
#pragma unroll
        for (int off = 1; off < 64; off <<= 1) {
            int t = __shfl_up(incl, off);
            if (lane >= off) incl += t;
        }
        if (lane == 63) wsum[wv] = incl;
        __syncthreads();
        int carry = s_carry;
        int woff = 0;
        for (int w = 0; w < wv; ++w) woff += wsum[w];
        int excl = carry + woff + (incl - tsum);
#pragma unroll
        for (int j = 0; j < ITEMS; ++j) {
            int i = idx0 + j;
            if (i < n) { row[i] = excl; cur[i] = excl; }
            excl += v[j];
        }
        __syncthreads();
        if (threadIdx.x == 0) s_carry = carry + wsum[0] + wsum[1] + wsum[2] + wsum[3];
        __syncthreads();
    }
    if (threadIdx.x == 0) row[n] = s_carry;
}

__global__ void bscan_kernel(const int* __restrict__ gcnt, int* __restrict__ bbase,
                             int* __restrict__ bcur, int n) {
    scan_block(gcnt, bbase, bcur, n);
}

__launch_bounds__(BLK)
__global__ void bbin_kernel(BJobs J, int* __restrict__ bcur, int2* __restrict__ ebuf, int NB) {
    __shared__ int lc[NBMAX];
    __shared__ int res[NBMAX];
    __shared__ int cur[NBMAX];
    int tid = threadIdx.x;
    for (int i = tid; i < NB; i += BLK) { lc[i] = 0; cur[i] = 0; }
    __syncthreads();
    int b = blockIdx.x, r = 0;
    while (b >= J.chunk_off[r + 1]) ++r;
    int e0 = (b - J.chunk_off[r]) * CHUNK_E;
    int e1 = min(e0 + CHUNK_E, J.E[r]);
    const int* __restrict__ src = J.src[r];
    const int* __restrict__ dst = J.dst[r];
    int base = J.nboff[r];
    for (int e = e0 + tid; e < e1; e += BLK)
        atomicAdd(&lc[base + (dst[e] >> SB_SHIFT)], 1);
    __syncthreads();
    for (int i = tid; i < NB; i += BLK)
        if (lc[i]) res[i] = atomicAdd(&bcur[i], lc[i]);
    __syncthreads();
    for (int e = e0 + tid; e < e1; e += BLK) {
        int s = src[e], d = dst[e];
        int bk = base + (d >> SB_SHIFT);
        int l = atomicAdd(&cur[bk], 1);
        ebuf[res[bk] + l] = make_int2(s, d);
    }
}

// One block per bucket: per-dst count, 128-wide scan, write row_ptr, place edges.
__launch_bounds__(BLK)
__global__ void bplace_kernel(BJobs J, const int* __restrict__ bbase,
                              const int2* __restrict__ ebuf,
                              int* __restrict__ ccsr, int* __restrict__ rowcat) {
    __shared__ int cnt[128];
    __shared__ int off[128];
    __shared__ int cur[128];
    int tid = threadIdx.x;
    int bk = blockIdx.x, r = 0;
    while (bk >= J.nboff[r + 1]) ++r;
    int dst0 = (bk - J.nboff[r]) << SB_SHIFT;
    int nd = J.ndst[r] - dst0;
    if (nd > 128) nd = 128;
    int ebase = bbase[bk], eend = bbase[bk + 1];
    if (tid < 128) cnt[tid] = 0;
    __syncthreads();
    for (int e = ebase + tid; e < eend; e += BLK)
        atomicAdd(&cnt[ebuf[e].y - dst0], 1);
    __syncthreads();
    if (tid < 128) off[tid] = cnt[tid];
    __syncthreads();
    for (int st = 1; st < 128; st <<= 1) {
        int v = 0;
        if (tid < 128 && tid >= st) v = off[tid - st];
        __syncthreads();
        if (tid < 128) off[tid] += v;
        __syncthreads();
    }
    int Eo = J.Eoff[r];
    int* __restrict__ row = rowcat + J.Roff[r];
    if (tid < nd) {
        int ex = off[tid] - cnt[tid];           // exclusive within-bucket offset
        row[dst0 + tid] = ebase + ex - Eo;      // relation-relative
        cur[tid] = ex;
    }
    if (tid == 0 && dst0 + nd == J.ndst[r])
        row[J.ndst[r]] = bbase[J.nboff[r + 1]] - Eo;
    __syncthreads();
    for (int e = ebase + tid; e < eend; e += BLK) {
        int2 sd = ebuf[e];
        int l = atomicAdd(&cur[sd.y - dst0], 1);
        ccsr[ebase + l] = sd.x;
    }
}

// ---------------- Dense transform: y = x @ W^T (+ b) ----------------
// Lane = output channel h. W row in 16 float4 VGPRs. x row addresses are
// wave-uniform (node derived from readfirstlane'd wave id) -> compiler
// scalarizes them to s_load: x streams through the SMEM pipe into SGPRs,
// feeding v_fma's scalar operand. No LDS at all.

struct TJobs {
    const float* x[6];
    const float* W[6];
    const float* b[6];
    float* y[6];
    int n[6];
    int boff[7];
};

__launch_bounds__(BLK)
__global__ void transform_kernel(TJobs J) {
    int b = blockIdx.x, j = 0;
    while (b >= J.boff[j + 1]) ++j;
    int n = J.n[j];
    const float* __restrict__ x = J.x[j];
    const float4* __restrict__ W4 = (const float4*)J.W[j];
    const float* bb = J.b[j];
    float* __restrict__ y = J.y[j];
    int tid = threadIdx.x, lane = tid & 63;
    int wv = __builtin_amdgcn_readfirstlane(tid >> 6);   // force uniform

    float4 Wreg[16];
#pragma unroll
    for (int dq = 0; dq < 16; ++dq) Wreg[dq] = W4[lane * 16 + dq];
    float bias = bb ? bb[lane] : 0.f;

    int base = (b - J.boff[j]) * TNT + wv * (TNT / 4);
    int end = min(base + TNT / 4, n);
    if (base >= end) return;

    int node = base;
    for (; node + 2 <= end; node += 2) {
        const float4* __restrict__ xr0 = (const float4*)(x + (size_t)node * 64);
        const float4* __restrict__ xr1 = (const float4*)(x + (size_t)(node + 1) * 64);
        float o0 = bias, o1 = bias;
#pragma unroll
        for (int dq = 0; dq < 16; ++dq) {
            float4 m0 = xr0[dq];
            float4 m1 = xr1[dq];
            float4 w = Wreg[dq];
            o0 += m0.x * w.x + m0.y * w.y + m0.z * w.z + m0.w * w.w;
            o1 += m1.x * w.x + m1.y * w.y + m1.z * w.z + m1.w * w.w;
        }
        y[(size_t)node * 64 + lane] = o0;
        y[(size_t)(node + 1) * 64 + lane] = o1;
    }
    if (node < end) {
        const float4* __restrict__ xr = (const float4*)(x + (size_t)node * 64);
        float o = bias;
#pragma unroll
        for (int dq = 0; dq < 16; ++dq) {
            float4 m = xr[dq];
            float4 w = Wreg[dq];
            o += m.x * w.x + m.y * w.y + m.z * w.z + m.w * w.w;
        }
        y[(size_t)node * 64 + lane] = o;
    }
}

// ---------------- Gather-mean + add (RMW into out), 8-way unrolled ----------------

struct GJobs {
    const float* y[3];
    const int* row[3];
    const int* csr[3];
    float* out[3];
    int n[3];
    int boff[4];
    int relu;
};

__launch_bounds__(BLK)
__global__ void gather_kernel(GJobs J) {
    int b = blockIdx.x, j = 0;
    while (b >= J.boff[j + 1]) ++j;
    int lane = threadIdx.x & 63, wv = threadIdx.x >> 6;
    int node = (b - J.boff[j]) * 4 + wv;
    if (node >= J.n[j]) return;
    const int* __restrict__ row = J.row[j];
    const int* __restrict__ csr = J.csr[j];
    const float* __restrict__ y = J.y[j];
    float* __restrict__ out = J.out[j];

    int e0 = row[node], e1 = row[node + 1];
    float a0 = 0.f, a1 = 0.f, a2 = 0.f, a3 = 0.f;
    float a4 = 0.f, a5 = 0.f, a6 = 0.f, a7 = 0.f;
    int e = e0;
    for (; e + 8 <= e1; e += 8) {
        int s0 = csr[e + 0], s1 = csr[e + 1], s2 = csr[e + 2], s3 = csr[e + 3];
        int s4 = csr[e + 4], s5 = csr[e + 5], s6 = csr[e + 6], s7 = csr[e + 7];
        a0 += y[(size_t)s0 * 64 + lane];
        a1 += y[(size_t)s1 * 64 + lane];
        a2 += y[(size_t)s2 * 64 + lane];
        a3 += y[(size_t)s3 * 64 + lane];
        a4 += y[(size_t)s4 * 64 + lane];
        a5 += y[(size_t)s5 * 64 + lane];
        a6 += y[(size_t)s6 * 64 + lane];
        a7 += y[(size_t)s7 * 64 + lane];
    }
    for (; e < e1; ++e) a0 += y[(size_t)csr[e] * 64 + lane];
    int deg = e1 - e0;
    float m = ((a0 + a1) + (a2 + a3)) + ((a4 + a5) + (a6 + a7));
    m = deg ? m / (float)deg : 0.f;
    size_t oi = (size_t)node * 64 + lane;
    float o = m + out[oi];
    if (J.relu) o = fmaxf(o, 0.f);
    out[oi] = o;
}

// ---------------- Host ----------------

extern "C" void kernel_launch(void* const* d_in, const int* in_sizes, int n_in,
                              void* d_out, int out_size, void* d_ws, size_t ws_size,
                              hipStream_t stream) {
    const float* x_user    = (const float*)d_in[0];
    const float* x_problem = (const float*)d_in[1];
    const float* x_topic   = (const float*)d_in[2];
    const int* up_src = (const int*)d_in[3];
    const int* up_dst = (const int*)d_in[4];
    const int* pt_src = (const int*)d_in[5];
    const int* pt_dst = (const int*)d_in[6];
    const int* pu_src = (const int*)d_in[7];
    const int* pu_dst = (const int*)d_in[8];
    const float* W1_up_l = (const float*)d_in[9];
    const float* W1_up_r = (const float*)d_in[10];
    const float* W1_pt_l = (const float*)d_in[11];
    const float* W1_pt_r = (const float*)d_in[12];
    const float* W1_pu_l = (const float*)d_in[13];
    const float* W1_pu_r = (const float*)d_in[14];
    const float* W2_up_l = (const float*)d_in[15];
    const float* W2_up_r = (const float*)d_in[16];
    const float* W2_pt_l = (const float*)d_in[17];
    const float* W2_pt_r = (const float*)d_in[18];
    const float* W2_pu_l = (const float*)d_in[19];
    const float* W2_pu_r = (const float*)d_in[20];
    const float* b1_up = (const float*)d_in[21];
    const float* b1_pt = (const float*)d_in[22];
    const float* b1_pu = (const float*)d_in[23];
    const float* b2_up = (const float*)d_in[24];
    const float* b2_pt = (const float*)d_in[25];
    const float* b2_pu = (const float*)d_in[26];

    int n_user = in_sizes[0] / 64;
    int n_problem = in_sizes[1] / 64;
    int n_topic = in_sizes[2] / 64;
    int E_up = in_sizes[3];
    int E_pt = in_sizes[5];
    int E_pu = in_sizes[7];
    int E_tot = E_up + E_pt + E_pu;

    float* o_user = (float*)d_out;
    float* o_problem = o_user + (size_t)n_user * 64;
    float* o_topic = o_problem + (size_t)n_problem * 64;

    char* ws = (char*)d_ws;
    size_t off = 0;
    auto alloc = [&](size_t bytes) -> void* {
        void* p = ws + off;
        off += (bytes + 255) & ~(size_t)255;
        return p;
    };
    float* h_user    = (float*)alloc((size_t)n_user * 64 * 4);
    float* h_problem = (float*)alloc((size_t)n_problem * 64 * 4);
    float* h_topic   = (float*)alloc((size_t)n_topic * 64 * 4);
    // y buffers; the front of this region doubles as ebuf (int2 per edge) during CSR build
    float* y_up = (float*)alloc((size_t)n_user * 64 * 4);
    float* y_pt = (float*)alloc((size_t)n_problem * 64 * 4);
    float* y_pu = (float*)alloc((size_t)n_problem * 64 * 4);
    int2* ebuf = (int2*)y_up;  // 16.5MB needed, 23MB available before first transform

    auto cdiv = [](int a, int b) { return (a + b - 1) / b; };

    // buckets: relations ordered [up(dst=problem), pt(dst=topic), pu(dst=user)]
    int nb0 = cdiv(n_problem, 128), nb1 = cdiv(n_topic, 128), nb2 = cdiv(n_user, 128);
    int NB = nb0 + nb1 + nb2;

    int* gcnt  = (int*)alloc((size_t)(NB) * 4);
    int* bbase = (int*)alloc((size_t)(NB + 1) * 4);
    int* bcur  = (int*)alloc((size_t)(NB + 1) * 4);
    int* rowcat = (int*)alloc((size_t)(n_problem + n_topic + n_user + 3) * 4);
    int* ccsr  = (int*)alloc((size_t)E_tot * 4);

    BJobs B;
    B.src[0] = up_src; B.dst[0] = up_dst; B.E[0] = E_up;
    B.src[1] = pt_src; B.dst[1] = pt_dst; B.E[1] = E_pt;
    B.src[2] = pu_src; B.dst[2] = pu_dst; B.E[2] = E_pu;
    B.Eoff[0] = 0; B.Eoff[1] = E_up; B.Eoff[2] = E_up + E_pt; B.Eoff[3] = E_tot;
    B.nboff[0] = 0; B.nboff[1] = nb0; B.nboff[2] = nb0 + nb1; B.nboff[3] = NB;
    B.ndst[0] = n_problem; B.ndst[1] = n_topic; B.ndst[2] = n_user;
    B.Roff[0] = 0; B.Roff[1] = n_problem + 1; B.Roff[2] = n_problem + 1 + n_topic + 1;
    B.chunk_off[0] = 0;
    for (int r = 0; r < 3; ++r) B.chunk_off[r + 1] = B.chunk_off[r] + cdiv(B.E[r], CHUNK_E);

    const int* row_up = rowcat + B.Roff[0];
    const int* row_pt = rowcat + B.Roff[1];
    const int* row_pu = rowcat + B.Roff[2];
    const int* csr_up = ccsr + B.Eoff[0];
    const int* csr_pt = ccsr + B.Eoff[1];
    const int* csr_pu = ccsr + B.Eoff[2];

    zero_kernel<<<cdiv(NB, 256), 256, 0, stream>>>(gcnt, NB);
    bhist_kernel<<<B.chunk_off[3], BLK, 0, stream>>>(B, gcnt, NB);
    bscan_kernel<<<1, BLK, 0, stream>>>(gcnt, bbase, bcur, NB);
    bbin_kernel<<<B.chunk_off[3], BLK, 0, stream>>>(B, bcur, ebuf, NB);
    bplace_kernel<<<B.nboff[3], BLK, 0, stream>>>(B, bbase, ebuf, ccsr, rowcat);

    // ---- layer 1 ----
    {
        TJobs T;
        const float* xs[6] = {x_user, x_problem, x_problem, x_problem, x_topic, x_user};
        const float* Ws[6] = {W1_up_l, W1_pt_l, W1_pu_l, W1_up_r, W1_pt_r, W1_pu_r};
        const float* bs[6] = {nullptr, nullptr, nullptr, b1_up, b1_pt, b1_pu};
        float* ys[6] = {y_up, y_pt, y_pu, h_problem, h_topic, h_user};
        int ns[6] = {n_user, n_problem, n_problem, n_problem, n_topic, n_user};
        T.boff[0] = 0;
        for (int j = 0; j < 6; ++j) {
            T.x[j] = xs[j]; T.W[j] = Ws[j]; T.b[j] = bs[j]; T.y[j] = ys[j]; T.n[j] = ns[j];
            T.boff[j + 1] = T.boff[j] + cdiv(ns[j], TNT);
        }
        transform_kernel<<<T.boff[6], BLK, 0, stream>>>(T);

        GJobs G;
        const float* gy[3] = {y_pu, y_up, y_pt};
        const int* gr[3] = {row_pu, row_up, row_pt};
        const int* gc[3] = {csr_pu, csr_up, csr_pt};
        float* go[3] = {h_user, h_problem, h_topic};
        int gn[3] = {n_user, n_problem, n_topic};
        G.boff[0] = 0;
        for (int j = 0; j < 3; ++j) {
            G.y[j] = gy[j]; G.row[j] = gr[j]; G.csr[j] = gc[j]; G.out[j] = go[j]; G.n[j] = gn[j];
            G.boff[j + 1] = G.boff[j] + cdiv(gn[j], 4);
        }
        G.relu = 1;
        gather_kernel<<<G.boff[3], BLK, 0, stream>>>(G);
    }

    // ---- layer 2 ----
    {
        TJobs T;
        const float* xs[6] = {h_user, h_problem, h_problem, h_problem, h_topic, h_user};
        const float* Ws[6] = {W2_up_l, W2_pt_l, W2_pu_l, W2_up_r, W2_pt_r, W2_pu_r};
        const float* bs[6] = {nullptr, nullptr, nullptr, b2_up, b2_pt, b2_pu};
        float* ys[6] = {y_up, y_pt, y_pu, o_problem, o_topic, o_user};
        int ns[6] = {n_user, n_problem, n_problem, n_problem, n_topic, n_user};
        T.boff[0] = 0;
        for (int j = 0; j < 6; ++j) {
            T.x[j] = xs[j]; T.W[j] = Ws[j]; T.b[j] = bs[j]; T.y[j] = ys[j]; T.n[j] = ns[j];
            T.boff[j + 1] = T.boff[j] + cdiv(ns[j], TNT);
        }
        transform_kernel<<<T.boff[6], BLK, 0, stream>>>(T);

        GJobs G;
        const float* gy[3] = {y_pu, y_up, y_pt};
        const int* gr[3] = {row_pu, row_up, row_pt};
        const int* gc[3] = {csr_pu, csr_up, csr_pt};
        float* go[3] = {o_user, o_problem, o_topic};
        int gn[3] = {n_user, n_problem, n_topic};
        G.boff[0] = 0;
        for (int j = 0; j < 3; ++j) {
            G.y[j] = gy[j]; G.row[j] = gr[j]; G.csr[j] = gc[j]; G.out[j] = go[j]; G.n[j] = gn[j];
            G.boff[j + 1] = G.boff[j] + cdiv(gn[j], 4);
        }
        G.relu = 0;
        gather_kernel<<<G.boff[3], BLK, 0, stream>>>(G);
    }
}

// Round 8
// 271.834 us; speedup vs baseline: 1.5713x; 1.4628x over previous
//
#include <hip/hip_runtime.h>

#define BLK 256
#define SB_SHIFT 7          // 128 dst per bucket
#define NBMAX 576
#define CHUNK_E 4096
#define TPAD 68             // floats per LDS row (272B, 16B-aligned)

// ---------------- generic zero ----------------

__global__ void zero_kernel(int* __restrict__ p, int n) {
    int i = blockIdx.x * blockDim.x + threadIdx.x;
    if (i < n) p[i] = 0;
}

// ---------------- bucketed CSR build ----------------

struct BJobs {
    const int* src[3];
    const int* dst[3];
    int E[3];
    int Eoff[4];       // concat edge offsets per relation
    int nboff[4];      // concat bucket-id offsets per relation
    int ndst[3];
    int Roff[3];       // row_ptr concat offsets per relation
    int chunk_off[4];  // chunk-block offsets per relation
};

__launch_bounds__(BLK)
__global__ void bhist_kernel(BJobs J, int* __restrict__ gcnt, int NB) {
    __shared__ int lc[NBMAX];
    int tid = threadIdx.x;
    for (int i = tid; i < NB; i += BLK) lc[i] = 0;
    __syncthreads();
    int b = blockIdx.x, r = 0;
    while (b >= J.chunk_off[r + 1]) ++r;
    int e0 = (b - J.chunk_off[r]) * CHUNK_E;
    int e1 = min(e0 + CHUNK_E, J.E[r]);
    const int* __restrict__ dst = J.dst[r];
    int base = J.nboff[r];
    for (int e = e0 + tid; e < e1; e += BLK)
        atomicAdd(&lc[base + (dst[e] >> SB_SHIFT)], 1);
    __syncthreads();
    for (int i = tid; i < NB; i += BLK)
        if (lc[i]) atomicAdd(&gcnt[i], lc[i]);
}

// Block-wide exclusive scan (256 threads, 16 items/thread/chunk).
__device__ void scan_block(const int* __restrict__ cnt, int* __restrict__ row,
                           int* __restrict__ cur, int n) {
    __shared__ int wsum[4];
    __shared__ int s_carry;
    const int ITEMS = 16;
    const int CHUNK = BLK * ITEMS;
    int lane = threadIdx.x & 63;
    int wv = threadIdx.x >> 6;
    if (threadIdx.x == 0) s_carry = 0;
    __syncthreads();
    for (int base = 0; base < n; base += CHUNK) {
        int idx0 = base + threadIdx.x * ITEMS;
        int v[ITEMS];
        int tsum = 0;
#pragma unroll
        for (int j = 0; j < ITEMS; ++j) {
            int i = idx0 + j;
            v[j] = (i < n) ? cnt[i] : 0;
            tsum += v[j];
        }
        int incl = tsum;
#pragma unroll
        for (int off = 1; off < 64; off <<= 1) {
            int t = __shfl_up(incl, off);
            if (lane >= off) incl += t;
        }
        if (lane == 63) wsum[wv] = incl;
        __syncthreads();
        int carry = s_carry;
        int woff = 0;
        for (int w = 0; w < wv; ++w) woff += wsum[w];
        int excl = carry + woff + (incl - tsum);
#pragma unroll
        for (int j = 0; j < ITEMS; ++j) {
            int i = idx0 + j;
            if (i < n) { row[i] = excl; cur[i] = excl; }
            excl += v[j];
        }
        __syncthreads();
        if (threadIdx.x == 0) s_carry = carry + wsum[0] + wsum[1] + wsum[2] + wsum[3];
        __syncthreads();
    }
    if (threadIdx.x == 0) row[n] = s_carry;
}

__global__ void bscan_kernel(const int* __restrict__ gcnt, int* __restrict__ bbase,
                             int* __restrict__ bcur, int n) {
    scan_block(gcnt, bbase, bcur, n);
}

__launch_bounds__(BLK)
__global__ void bbin_kernel(BJobs J, int* __restrict__ bcur, int2* __restrict__ ebuf, int NB) {
    __shared__ int lc[NBMAX];
    __shared__ int res[NBMAX];
    __shared__ int cur[NBMAX];
    int tid = threadIdx.x;
    for (int i = tid; i < NB; i += BLK) { lc[i] = 0; cur[i] = 0; }
    __syncthreads();
    int b = blockIdx.x, r = 0;
    while (b >= J.chunk_off[r + 1]) ++r;
    int e0 = (b - J.chunk_off[r]) * CHUNK_E;
    int e1 = min(e0 + CHUNK_E, J.E[r]);
    const int* __restrict__ src = J.src[r];
    const int* __restrict__ dst = J.dst[r];
    int base = J.nboff[r];
    for (int e = e0 + tid; e < e1; e += BLK)
        atomicAdd(&lc[base + (dst[e] >> SB_SHIFT)], 1);
    __syncthreads();
    for (int i = tid; i < NB; i += BLK)
        if (lc[i]) res[i] = atomicAdd(&bcur[i], lc[i]);
    __syncthreads();
    for (int e = e0 + tid; e < e1; e += BLK) {
        int s = src[e], d = dst[e];
        int bk = base + (d >> SB_SHIFT);
        int l = atomicAdd(&cur[bk], 1);
        ebuf[res[bk] + l] = make_int2(s, d);
    }
}

// One block per bucket: per-dst count, 128-wide scan, write row_ptr, place edges.
__launch_bounds__(BLK)
__global__ void bplace_kernel(BJobs J, const int* __restrict__ bbase,
                              const int2* __restrict__ ebuf,
                              int* __restrict__ ccsr, int* __restrict__ rowcat) {
    __shared__ int cnt[128];
    __shared__ int off[128];
    __shared__ int cur[128];
    int tid = threadIdx.x;
    int bk = blockIdx.x, r = 0;
    while (bk >= J.nboff[r + 1]) ++r;
    int dst0 = (bk - J.nboff[r]) << SB_SHIFT;
    int nd = J.ndst[r] - dst0;
    if (nd > 128) nd = 128;
    int ebase = bbase[bk], eend = bbase[bk + 1];
    if (tid < 128) cnt[tid] = 0;
    __syncthreads();
    for (int e = ebase + tid; e < eend; e += BLK)
        atomicAdd(&cnt[ebuf[e].y - dst0], 1);
    __syncthreads();
    if (tid < 128) off[tid] = cnt[tid];
    __syncthreads();
    for (int st = 1; st < 128; st <<= 1) {
        int v = 0;
        if (tid < 128 && tid >= st) v = off[tid - st];
        __syncthreads();
        if (tid < 128) off[tid] += v;
        __syncthreads();
    }
    int Eo = J.Eoff[r];
    int* __restrict__ row = rowcat + J.Roff[r];
    if (tid < nd) {
        int ex = off[tid] - cnt[tid];           // exclusive within-bucket offset
        row[dst0 + tid] = ebase + ex - Eo;      // relation-relative
        cur[tid] = ex;
    }
    if (tid == 0 && dst0 + nd == J.ndst[r])
        row[J.ndst[r]] = bbase[J.nboff[r + 1]] - Eo;
    __syncthreads();
    for (int e = ebase + tid; e < eend; e += BLK) {
        int2 sd = ebuf[e];
        int l = atomicAdd(&cur[sd.y - dst0], 1);
        ccsr[ebase + l] = sd.x;
    }
}

// ---------------- Dense transform: y = x @ W^T (+ b) ----------------
// GEMM register tile: block = 128 nodes x 64 h, thread = 8 nodes x 4 h.
// x staged row-major [128][TPAD]; W staged transposed wT[k][TPAD].
// Per-lane-distinct b128 LDS reads; node map n=ty+16i keeps ty-groups 4
// banks apart (conflict-free); k-loop NOT fully unrolled (no VGPR spill).

struct TJobs {
    const float* x[6];
    const float* W[6];
    const float* b[6];
    float* y[6];
    int n[6];
    int boff[7];
};

__launch_bounds__(BLK)
__global__ void transform_kernel(TJobs J) {
    __shared__ float xlds[128 * TPAD];   // 34816 B
    __shared__ float wlds[64 * TPAD];    // 17408 B
    int b = blockIdx.x, j = 0;
    while (b >= J.boff[j + 1]) ++j;
    int n = J.n[j];
    int n0 = (b - J.boff[j]) * 128;
    const float4* __restrict__ x4 = (const float4*)J.x[j];
    const float4* __restrict__ W4 = (const float4*)J.W[j];
    const float* bb = J.b[j];
    float* __restrict__ y = J.y[j];
    int t = threadIdx.x;

    // stage x: 2048 float4, coalesced; linear LDS rows (stride TPAD)
#pragma unroll
    for (int q = 0; q < 8; ++q) {
        int idx = q * 256 + t;
        int node = idx >> 4, kq = idx & 15;
        float4 v = make_float4(0.f, 0.f, 0.f, 0.f);
        if (n0 + node < n) v = x4[(size_t)(n0 + node) * 16 + kq];
        *(float4*)&xlds[node * TPAD + kq * 4] = v;
    }
    // stage W transposed: wT[k][h]
#pragma unroll
    for (int q = 0; q < 4; ++q) {
        int idx = q * 256 + t;          // 1024 float4
        int h = idx >> 4, kq = idx & 15;
        float4 v = W4[idx];
        wlds[(kq * 4 + 0) * TPAD + h] = v.x;
        wlds[(kq * 4 + 1) * TPAD + h] = v.y;
        wlds[(kq * 4 + 2) * TPAD + h] = v.z;
        wlds[(kq * 4 + 3) * TPAD + h] = v.w;
    }
    __syncthreads();

    int tx = t & 15, ty = t >> 4;       // tx: h-quad, ty: node phase (0..15)
    float4 bias4 = make_float4(0.f, 0.f, 0.f, 0.f);
    if (bb) bias4 = *(const float4*)&bb[tx * 4];
    float acc[8][4];
#pragma unroll
    for (int i = 0; i < 8; ++i) {
        acc[i][0] = bias4.x; acc[i][1] = bias4.y;
        acc[i][2] = bias4.z; acc[i][3] = bias4.w;
    }

    for (int k4 = 0; k4 < 16; ++k4) {
        float4 wv0 = *(const float4*)&wlds[(k4 * 4 + 0) * TPAD + tx * 4];
        float4 wv1 = *(const float4*)&wlds[(k4 * 4 + 1) * TPAD + tx * 4];
        float4 wv2 = *(const float4*)&wlds[(k4 * 4 + 2) * TPAD + tx * 4];
        float4 wv3 = *(const float4*)&wlds[(k4 * 4 + 3) * TPAD + tx * 4];
#pragma unroll
        for (int i = 0; i < 8; ++i) {
            float4 xv = *(const float4*)&xlds[(ty + 16 * i) * TPAD + k4 * 4];
            acc[i][0] += xv.x * wv0.x + xv.y * wv1.x + xv.z * wv2.x + xv.w * wv3.x;
            acc[i][1] += xv.x * wv0.y + xv.y * wv1.y + xv.z * wv2.y + xv.w * wv3.y;
            acc[i][2] += xv.x * wv0.z + xv.y * wv1.z + xv.z * wv2.z + xv.w * wv3.z;
            acc[i][3] += xv.x * wv0.w + xv.y * wv1.w + xv.z * wv2.w + xv.w * wv3.w;
        }
    }

#pragma unroll
    for (int i = 0; i < 8; ++i) {
        int node = n0 + ty + 16 * i;
        if (node < n) {
            float4 o = make_float4(acc[i][0], acc[i][1], acc[i][2], acc[i][3]);
            ((float4*)y)[(size_t)node * 16 + tx] = o;
        }
    }
}

// ---------------- Gather-mean + add (RMW into out), 8-way unrolled ----------------

struct GJobs {
    const float* y[3];
    const int* row[3];
    const int* csr[3];
    float* out[3];
    int n[3];
    int boff[4];
    int relu;
};

__launch_bounds__(BLK)
__global__ void gather_kernel(GJobs J) {
    int b = blockIdx.x, j = 0;
    while (b >= J.boff[j + 1]) ++j;
    int lane = threadIdx.x & 63, wv = threadIdx.x >> 6;
    int node = (b - J.boff[j]) * 4 + wv;
    if (node >= J.n[j]) return;
    const int* __restrict__ row = J.row[j];
    const int* __restrict__ csr = J.csr[j];
    const float* __restrict__ y = J.y[j];
    float* __restrict__ out = J.out[j];

    int e0 = row[node], e1 = row[node + 1];
    float a0 = 0.f, a1 = 0.f, a2 = 0.f, a3 = 0.f;
    float a4 = 0.f, a5 = 0.f, a6 = 0.f, a7 = 0.f;
    int e = e0;
    for (; e + 8 <= e1; e += 8) {
        int s0 = csr[e + 0], s1 = csr[e + 1], s2 = csr[e + 2], s3 = csr[e + 3];
        int s4 = csr[e + 4], s5 = csr[e + 5], s6 = csr[e + 6], s7 = csr[e + 7];
        a0 += y[(size_t)s0 * 64 + lane];
        a1 += y[(size_t)s1 * 64 + lane];
        a2 += y[(size_t)s2 * 64 + lane];
        a3 += y[(size_t)s3 * 64 + lane];
        a4 += y[(size_t)s4 * 64 + lane];
        a5 += y[(size_t)s5 * 64 + lane];
        a6 += y[(size_t)s6 * 64 + lane];
        a7 += y[(size_t)s7 * 64 + lane];
    }
    for (; e < e1; ++e) a0 += y[(size_t)csr[e] * 64 + lane];
    int deg = e1 - e0;
    float m = ((a0 + a1) + (a2 + a3)) + ((a4 + a5) + (a6 + a7));
    m = deg ? m / (float)deg : 0.f;
    size_t oi = (size_t)node * 64 + lane;
    float o = m + out[oi];
    if (J.relu) o = fmaxf(o, 0.f);
    out[oi] = o;
}

// ---------------- Host ----------------

extern "C" void kernel_launch(void* const* d_in, const int* in_sizes, int n_in,
                              void* d_out, int out_size, void* d_ws, size_t ws_size,
                              hipStream_t stream) {
    const float* x_user    = (const float*)d_in[0];
    const float* x_problem = (const float*)d_in[1];
    const float* x_topic   = (const float*)d_in[2];
    const int* up_src = (const int*)d_in[3];
    const int* up_dst = (const int*)d_in[4];
    const int* pt_src = (const int*)d_in[5];
    const int* pt_dst = (const int*)d_in[6];
    const int* pu_src = (const int*)d_in[7];
    const int* pu_dst = (const int*)d_in[8];
    const float* W1_up_l = (const float*)d_in[9];
    const float* W1_up_r = (const float*)d_in[10];
    const float* W1_pt_l = (const float*)d_in[11];
    const float* W1_pt_r = (const float*)d_in[12];
    const float* W1_pu_l = (const float*)d_in[13];
    const float* W1_pu_r = (const float*)d_in[14];
    const float* W2_up_l = (const float*)d_in[15];
    const float* W2_up_r = (const float*)d_in[16];
    const float* W2_pt_l = (const float*)d_in[17];
    const float* W2_pt_r = (const float*)d_in[18];
    const float* W2_pu_l = (const float*)d_in[19];
    const float* W2_pu_r = (const float*)d_in[20];
    const float* b1_up = (const float*)d_in[21];
    const float* b1_pt = (const float*)d_in[22];
    const float* b1_pu = (const float*)d_in[23];
    const float* b2_up = (const float*)d_in[24];
    const float* b2_pt = (const float*)d_in[25];
    const float* b2_pu = (const float*)d_in[26];

    int n_user = in_sizes[0] / 64;
    int n_problem = in_sizes[1] / 64;
    int n_topic = in_sizes[2] / 64;
    int E_up = in_sizes[3];
    int E_pt = in_sizes[5];
    int E_pu = in_sizes[7];
    int E_tot = E_up + E_pt + E_pu;

    float* o_user = (float*)d_out;
    float* o_problem = o_user + (size_t)n_user * 64;
    float* o_topic = o_problem + (size_t)n_problem * 64;

    char* ws = (char*)d_ws;
    size_t off = 0;
    auto alloc = [&](size_t bytes) -> void* {
        void* p = ws + off;
        off += (bytes + 255) & ~(size_t)255;
        return p;
    };
    float* h_user    = (float*)alloc((size_t)n_user * 64 * 4);
    float* h_problem = (float*)alloc((size_t)n_problem * 64 * 4);
    float* h_topic   = (float*)alloc((size_t)n_topic * 64 * 4);
    // y buffers; the front of this region doubles as ebuf (int2 per edge) during CSR build
    float* y_up = (float*)alloc((size_t)n_user * 64 * 4);
    float* y_pt = (float*)alloc((size_t)n_problem * 64 * 4);
    float* y_pu = (float*)alloc((size_t)n_problem * 64 * 4);
    int2* ebuf = (int2*)y_up;  // 16.5MB needed, 23MB available before first transform

    auto cdiv = [](int a, int b) { return (a + b - 1) / b; };

    // buckets: relations ordered [up(dst=problem), pt(dst=topic), pu(dst=user)]
    int nb0 = cdiv(n_problem, 128), nb1 = cdiv(n_topic, 128), nb2 = cdiv(n_user, 128);
    int NB = nb0 + nb1 + nb2;

    int* gcnt  = (int*)alloc((size_t)(NB) * 4);
    int* bbase = (int*)alloc((size_t)(NB + 1) * 4);
    int* bcur  = (int*)alloc((size_t)(NB + 1) * 4);
    int* rowcat = (int*)alloc((size_t)(n_problem + n_topic + n_user + 3) * 4);
    int* ccsr  = (int*)alloc((size_t)E_tot * 4);

    BJobs B;
    B.src[0] = up_src; B.dst[0] = up_dst; B.E[0] = E_up;
    B.src[1] = pt_src; B.dst[1] = pt_dst; B.E[1] = E_pt;
    B.src[2] = pu_src; B.dst[2] = pu_dst; B.E[2] = E_pu;
    B.Eoff[0] = 0; B.Eoff[1] = E_up; B.Eoff[2] = E_up + E_pt; B.Eoff[3] = E_tot;
    B.nboff[0] = 0; B.nboff[1] = nb0; B.nboff[2] = nb0 + nb1; B.nboff[3] = NB;
    B.ndst[0] = n_problem; B.ndst[1] = n_topic; B.ndst[2] = n_user;
    B.Roff[0] = 0; B.Roff[1] = n_problem + 1; B.Roff[2] = n_problem + 1 + n_topic + 1;
    B.chunk_off[0] = 0;
    for (int r = 0; r < 3; ++r) B.chunk_off[r + 1] = B.chunk_off[r] + cdiv(B.E[r], CHUNK_E);

    const int* row_up = rowcat + B.Roff[0];
    const int* row_pt = rowcat + B.Roff[1];
    const int* row_pu = rowcat + B.Roff[2];
    const int* csr_up = ccsr + B.Eoff[0];
    const int* csr_pt = ccsr + B.Eoff[1];
    const int* csr_pu = ccsr + B.Eoff[2];

    zero_kernel<<<cdiv(NB, 256), 256, 0, stream>>>(gcnt, NB);
    bhist_kernel<<<B.chunk_off[3], BLK, 0, stream>>>(B, gcnt, NB);
    bscan_kernel<<<1, BLK, 0, stream>>>(gcnt, bbase, bcur, NB);
    bbin_kernel<<<B.chunk_off[3], BLK, 0, stream>>>(B, bcur, ebuf, NB);
    bplace_kernel<<<B.nboff[3], BLK, 0, stream>>>(B, bbase, ebuf, ccsr, rowcat);

    // ---- layer 1 ----
    {
        TJobs T;
        const float* xs[6] = {x_user, x_problem, x_problem, x_problem, x_topic, x_user};
        const float* Ws[6] = {W1_up_l, W1_pt_l, W1_pu_l, W1_up_r, W1_pt_r, W1_pu_r};
        const float* bs[6] = {nullptr, nullptr, nullptr, b1_up, b1_pt, b1_pu};
        float* ys[6] = {y_up, y_pt, y_pu, h_problem, h_topic, h_user};
        int ns[6] = {n_user, n_problem, n_problem, n_problem, n_topic, n_user};
        T.boff[0] = 0;
        for (int j = 0; j < 6; ++j) {
            T.x[j] = xs[j]; T.W[j] = Ws[j]; T.b[j] = bs[j]; T.y[j] = ys[j]; T.n[j] = ns[j];
            T.boff[j + 1] = T.boff[j] + cdiv(ns[j], 128);
        }
        transform_kernel<<<T.boff[6], BLK, 0, stream>>>(T);

        GJobs G;
        const float* gy[3] = {y_pu, y_up, y_pt};
        const int* gr[3] = {row_pu, row_up, row_pt};
        const int* gc[3] = {csr_pu, csr_up, csr_pt};
        float* go[3] = {h_user, h_problem, h_topic};
        int gn[3] = {n_user, n_problem, n_topic};
        G.boff[0] = 0;
        for (int j = 0; j < 3; ++j) {
            G.y[j] = gy[j]; G.row[j] = gr[j]; G.csr[j] = gc[j]; G.out[j] = go[j]; G.n[j] = gn[j];
            G.boff[j + 1] = G.boff[j] + cdiv(gn[j], 4);
        }
        G.relu = 1;
        gather_kernel<<<G.boff[3], BLK, 0, stream>>>(G);
    }

    // ---- layer 2 ----
    {
        TJobs T;
        const float* xs[6] = {h_user, h_problem, h_problem, h_problem, h_topic, h_user};
        const float* Ws[6] = {W2_up_l, W2_pt_l, W2_pu_l, W2_up_r, W2_pt_r, W2_pu_r};
        const float* bs[6] = {nullptr, nullptr, nullptr, b2_up, b2_pt, b2_pu};
        float* ys[6] = {y_up, y_pt, y_pu, o_problem, o_topic, o_user};
        int ns[6] = {n_user, n_problem, n_problem, n_problem, n_topic, n_user};
        T.boff[0] = 0;
        for (int j = 0; j < 6; ++j) {
            T.x[j] = xs[j]; T.W[j] = Ws[j]; T.b[j] = bs[j]; T.y[j] = ys[j]; T.n[j] = ns[j];
            T.boff[j + 1] = T.boff[j] + cdiv(ns[j], 128);
        }
        transform_kernel<<<T.boff[6], BLK, 0, stream>>>(T);

        GJobs G;
        const float* gy[3] = {y_pu, y_up, y_pt};
        const int* gr[3] = {row_pu, row_up, row_pt};
        const int* gc[3] = {csr_pu, csr_up, csr_pt};
        float* go[3] = {o_user, o_problem, o_topic};
        int gn[3] = {n_user, n_problem, n_topic};
        G.boff[0] = 0;
        for (int j = 0; j < 3; ++j) {
            G.y[j] = gy[j]; G.row[j] = gr[j]; G.csr[j] = gc[j]; G.out[j] = go[j]; G.n[j] = gn[j];
            G.boff[j + 1] = G.boff[j] + cdiv(gn[j], 4);
        }
        G.relu = 0;
        gather_kernel<<<G.boff[3], BLK, 0, stream>>>(G);
    }
}

// Round 9
// 252.310 us; speedup vs baseline: 1.6928x; 1.0774x over previous
//
#include <hip/hip_runtime.h>

#define BLK 256
#define SB_SHIFT 7          // 128 dst per bucket
#define NBMAX 576
#define CHUNK_E 4096
#define TPAD 68             // floats per LDS row (272B, 16B-aligned)

__device__ inline unsigned short f2bf(float f) {
    union { float f; unsigned u; } c; c.f = f;
    unsigned u = c.u + (0x7fffu + ((c.u >> 16) & 1u));   // RNE
    return (unsigned short)(u >> 16);
}
__device__ inline float bf2f(unsigned short h) {
    union { unsigned u; float f; } c; c.u = ((unsigned)h) << 16;
    return c.f;
}

// ---------------- generic zero ----------------

__global__ void zero_kernel(int* __restrict__ p, int n) {
    int i = blockIdx.x * blockDim.x + threadIdx.x;
    if (i < n) p[i] = 0;
}

// ---------------- bucketed CSR build ----------------

struct BJobs {
    const int* src[3];
    const int* dst[3];
    int E[3];
    int Eoff[4];       // concat edge offsets per relation
    int nboff[4];      // concat bucket-id offsets per relation
    int ndst[3];
    int Roff[3];       // row_ptr concat offsets per relation
    int chunk_off[4];  // chunk-block offsets per relation
};

__launch_bounds__(BLK)
__global__ void bhist_kernel(BJobs J, int* __restrict__ gcnt, int NB) {
    __shared__ int lc[NBMAX];
    int tid = threadIdx.x;
    for (int i = tid; i < NB; i += BLK) lc[i] = 0;
    __syncthreads();
    int b = blockIdx.x, r = 0;
    while (b >= J.chunk_off[r + 1]) ++r;
    int e0 = (b - J.chunk_off[r]) * CHUNK_E;
    int e1 = min(e0 + CHUNK_E, J.E[r]);
    const int* __restrict__ dst = J.dst[r];
    int base = J.nboff[r];
    for (int e = e0 + tid; e < e1; e += BLK)
        atomicAdd(&lc[base + (dst[e] >> SB_SHIFT)], 1);
    __syncthreads();
    for (int i = tid; i < NB; i += BLK)
        if (lc[i]) atomicAdd(&gcnt[i], lc[i]);
}

// Block-wide exclusive scan (256 threads, 16 items/thread/chunk).
__device__ void scan_block(const int* __restrict__ cnt, int* __restrict__ row,
                           int* __restrict__ cur, int n) {
    __shared__ int wsum[4];
    __shared__ int s_carry;
    const int ITEMS = 16;
    const int CHUNK = BLK * ITEMS;
    int lane = threadIdx.x & 63;
    int wv = threadIdx.x >> 6;
    if (threadIdx.x == 0) s_carry = 0;
    __syncthreads();
    for (int base = 0; base < n; base += CHUNK) {
        int idx0 = base + threadIdx.x * ITEMS;
        int v[ITEMS];
        int tsum = 0;
#pragma unroll
        for (int j = 0; j < ITEMS; ++j) {
            int i = idx0 + j;
            v[j] = (i < n) ? cnt[i] : 0;
            tsum += v[j];
        }
        int incl = tsum;
#pragma unroll
        for (int off = 1; off < 64; off <<= 1) {
            int t = __shfl_up(incl, off);
            if (lane >= off) incl += t;
        }
        if (lane == 63) wsum[wv] = incl;
        __syncthreads();
        int carry = s_carry;
        int woff = 0;
        for (int w = 0; w < wv; ++w) woff += wsum[w];
        int excl = carry + woff + (incl - tsum);
#pragma unroll
        for (int j = 0; j < ITEMS; ++j) {
            int i = idx0 + j;
            if (i < n) { row[i] = excl; cur[i] = excl; }
            excl += v[j];
        }
        __syncthreads();
        if (threadIdx.x == 0) s_carry = carry + wsum[0] + wsum[1] + wsum[2] + wsum[3];
        __syncthreads();
    }
    if (threadIdx.x == 0) row[n] = s_carry;
}

__global__ void bscan_kernel(const int* __restrict__ gcnt, int* __restrict__ bbase,
                             int* __restrict__ bcur, int n) {
    scan_block(gcnt, bbase, bcur, n);
}

// ebuf entry: (src << SB_SHIFT) | dst_local  (src < 2^17, dst_local < 2^7)
__launch_bounds__(BLK)
__global__ void bbin_kernel(BJobs J, int* __restrict__ bcur, int* __restrict__ ebuf, int NB) {
    __shared__ int lc[NBMAX];
    __shared__ int res[NBMAX];
    __shared__ int cur[NBMAX];
    int tid = threadIdx.x;
    for (int i = tid; i < NB; i += BLK) { lc[i] = 0; cur[i] = 0; }
    __syncthreads();
    int b = blockIdx.x, r = 0;
    while (b >= J.chunk_off[r + 1]) ++r;
    int e0 = (b - J.chunk_off[r]) * CHUNK_E;
    int e1 = min(e0 + CHUNK_E, J.E[r]);
    const int* __restrict__ src = J.src[r];
    const int* __restrict__ dst = J.dst[r];
    int base = J.nboff[r];
    for (int e = e0 + tid; e < e1; e += BLK)
        atomicAdd(&lc[base + (dst[e] >> SB_SHIFT)], 1);
    __syncthreads();
    for (int i = tid; i < NB; i += BLK)
        if (lc[i]) res[i] = atomicAdd(&bcur[i], lc[i]);
    __syncthreads();
    for (int e = e0 + tid; e < e1; e += BLK) {
        int s = src[e], d = dst[e];
        int bk = base + (d >> SB_SHIFT);
        int l = atomicAdd(&cur[bk], 1);
        ebuf[res[bk] + l] = (s << SB_SHIFT) | (d & 127);
    }
}

// One block per bucket: per-dst count, 128-wide scan, write row_ptr, place edges.
__launch_bounds__(BLK)
__global__ void bplace_kernel(BJobs J, const int* __restrict__ bbase,
                              const int* __restrict__ ebuf,
                              int* __restrict__ ccsr, int* __restrict__ rowcat) {
    __shared__ int cnt[128];
    __shared__ int off[128];
    __shared__ int cur[128];
    int tid = threadIdx.x;
    int bk = blockIdx.x, r = 0;
    while (bk >= J.nboff[r + 1]) ++r;
    int dst0 = (bk - J.nboff[r]) << SB_SHIFT;
    int nd = J.ndst[r] - dst0;
    if (nd > 128) nd = 128;
    int ebase = bbase[bk], eend = bbase[bk + 1];
    if (tid < 128) cnt[tid] = 0;
    __syncthreads();
    for (int e = ebase + tid; e < eend; e += BLK)
        atomicAdd(&cnt[ebuf[e] & 127], 1);
    __syncthreads();
    if (tid < 128) off[tid] = cnt[tid];
    __syncthreads();
    for (int st = 1; st < 128; st <<= 1) {
        int v = 0;
        if (tid < 128 && tid >= st) v = off[tid - st];
        __syncthreads();
        if (tid < 128) off[tid] += v;
        __syncthreads();
    }
    int Eo = J.Eoff[r];
    int* __restrict__ row = rowcat + J.Roff[r];
    if (tid < nd) {
        int ex = off[tid] - cnt[tid];           // exclusive within-bucket offset
        row[dst0 + tid] = ebase + ex - Eo;      // relation-relative
        cur[tid] = ex;
    }
    if (tid == 0 && dst0 + nd == J.ndst[r])
        row[J.ndst[r]] = bbase[J.nboff[r + 1]] - Eo;
    __syncthreads();
    for (int e = ebase + tid; e < eend; e += BLK) {
        int sd = ebuf[e];
        int l = atomicAdd(&cur[sd & 127], 1);
        ccsr[ebase + l] = sd >> SB_SHIFT;
    }
}

// ---------------- Dense transform: y = x @ W^T (+ b) ----------------
// GEMM register tile: block = 128 nodes x 64 h, thread = 8 nodes x 4 h.
// Output dtype per job: f32 (self-term, into out buffers) or bf16
// (neighbor-term y buffers, halves the gather's read traffic).

struct TJobs {
    const float* x[6];
    const float* W[6];
    const float* b[6];
    void* y[6];
    int n[6];
    int obf16[6];
    int boff[7];
};

__launch_bounds__(BLK)
__global__ void transform_kernel(TJobs J) {
    __shared__ float xlds[128 * TPAD];   // 34816 B
    __shared__ float wlds[64 * TPAD];    // 17408 B
    int b = blockIdx.x, j = 0;
    while (b >= J.boff[j + 1]) ++j;
    int n = J.n[j];
    int n0 = (b - J.boff[j]) * 128;
    const float4* __restrict__ x4 = (const float4*)J.x[j];
    const float4* __restrict__ W4 = (const float4*)J.W[j];
    const float* bb = J.b[j];
    int t = threadIdx.x;

    // stage x: 2048 float4, coalesced; linear LDS rows (stride TPAD)
#pragma unroll
    for (int q = 0; q < 8; ++q) {
        int idx = q * 256 + t;
        int node = idx >> 4, kq = idx & 15;
        float4 v = make_float4(0.f, 0.f, 0.f, 0.f);
        if (n0 + node < n) v = x4[(size_t)(n0 + node) * 16 + kq];
        *(float4*)&xlds[node * TPAD + kq * 4] = v;
    }
    // stage W transposed: wT[k][h]
#pragma unroll
    for (int q = 0; q < 4; ++q) {
        int idx = q * 256 + t;          // 1024 float4
        int h = idx >> 4, kq = idx & 15;
        float4 v = W4[idx];
        wlds[(kq * 4 + 0) * TPAD + h] = v.x;
        wlds[(kq * 4 + 1) * TPAD + h] = v.y;
        wlds[(kq * 4 + 2) * TPAD + h] = v.z;
        wlds[(kq * 4 + 3) * TPAD + h] = v.w;
    }
    __syncthreads();

    int tx = t & 15, ty = t >> 4;       // tx: h-quad, ty: node phase (0..15)
    float4 bias4 = make_float4(0.f, 0.f, 0.f, 0.f);
    if (bb) bias4 = *(const float4*)&bb[tx * 4];
    float acc[8][4];
#pragma unroll
    for (int i = 0; i < 8; ++i) {
        acc[i][0] = bias4.x; acc[i][1] = bias4.y;
        acc[i][2] = bias4.z; acc[i][3] = bias4.w;
    }

    for (int k4 = 0; k4 < 16; ++k4) {
        float4 wv0 = *(const float4*)&wlds[(k4 * 4 + 0) * TPAD + tx * 4];
        float4 wv1 = *(const float4*)&wlds[(k4 * 4 + 1) * TPAD + tx * 4];
        float4 wv2 = *(const float4*)&wlds[(k4 * 4 + 2) * TPAD + tx * 4];
        float4 wv3 = *(const float4*)&wlds[(k4 * 4 + 3) * TPAD + tx * 4];
#pragma unroll
        for (int i = 0; i < 8; ++i) {
            float4 xv = *(const float4*)&xlds[(ty + 16 * i) * TPAD + k4 * 4];
            acc[i][0] += xv.x * wv0.x + xv.y * wv1.x + xv.z * wv2.x + xv.w * wv3.x;
            acc[i][1] += xv.x * wv0.y + xv.y * wv1.y + xv.z * wv2.y + xv.w * wv3.y;
            acc[i][2] += xv.x * wv0.z + xv.y * wv1.z + xv.z * wv2.z + xv.w * wv3.z;
            acc[i][3] += xv.x * wv0.w + xv.y * wv1.w + xv.z * wv2.w + xv.w * wv3.w;
        }
    }

    if (J.obf16[j]) {
        unsigned short* __restrict__ yb = (unsigned short*)J.y[j];
#pragma unroll
        for (int i = 0; i < 8; ++i) {
            int node = n0 + ty + 16 * i;
            if (node < n) {
                ushort4 o;
                o.x = f2bf(acc[i][0]); o.y = f2bf(acc[i][1]);
                o.z = f2bf(acc[i][2]); o.w = f2bf(acc[i][3]);
                *(ushort4*)&yb[(size_t)node * 64 + tx * 4] = o;
            }
        }
    } else {
        float* __restrict__ y = (float*)J.y[j];
#pragma unroll
        for (int i = 0; i < 8; ++i) {
            int node = n0 + ty + 16 * i;
            if (node < n) {
                float4 o = make_float4(acc[i][0], acc[i][1], acc[i][2], acc[i][3]);
                ((float4*)y)[(size_t)node * 16 + tx] = o;
            }
        }
    }
}

// ---------------- Gather-mean + add (RMW into out), 8-way unrolled, bf16 y ----------------

struct GJobs {
    const unsigned short* y[3];
    const int* row[3];
    const int* csr[3];
    float* out[3];
    int n[3];
    int boff[4];
    int relu;
};

__launch_bounds__(BLK)
__global__ void gather_kernel(GJobs J) {
    int b = blockIdx.x, j = 0;
    while (b >= J.boff[j + 1]) ++j;
    int lane = threadIdx.x & 63, wv = threadIdx.x >> 6;
    int node = (b - J.boff[j]) * 4 + wv;
    if (node >= J.n[j]) return;
    const int* __restrict__ row = J.row[j];
    const int* __restrict__ csr = J.csr[j];
    const unsigned short* __restrict__ y = J.y[j];
    float* __restrict__ out = J.out[j];

    int e0 = row[node], e1 = row[node + 1];
    float a0 = 0.f, a1 = 0.f, a2 = 0.f, a3 = 0.f;
    float a4 = 0.f, a5 = 0.f, a6 = 0.f, a7 = 0.f;
    int e = e0;
    for (; e + 8 <= e1; e += 8) {
        int s0 = csr[e + 0], s1 = csr[e + 1], s2 = csr[e + 2], s3 = csr[e + 3];
        int s4 = csr[e + 4], s5 = csr[e + 5], s6 = csr[e + 6], s7 = csr[e + 7];
        a0 += bf2f(y[(size_t)s0 * 64 + lane]);
        a1 += bf2f(y[(size_t)s1 * 64 + lane]);
        a2 += bf2f(y[(size_t)s2 * 64 + lane]);
        a3 += bf2f(y[(size_t)s3 * 64 + lane]);
        a4 += bf2f(y[(size_t)s4 * 64 + lane]);
        a5 += bf2f(y[(size_t)s5 * 64 + lane]);
        a6 += bf2f(y[(size_t)s6 * 64 + lane]);
        a7 += bf2f(y[(size_t)s7 * 64 + lane]);
    }
    for (; e < e1; ++e) a0 += bf2f(y[(size_t)csr[e] * 64 + lane]);
    int deg = e1 - e0;
    float m = ((a0 + a1) + (a2 + a3)) + ((a4 + a5) + (a6 + a7));
    m = deg ? m / (float)deg : 0.f;
    size_t oi = (size_t)node * 64 + lane;
    float o = m + out[oi];
    if (J.relu) o = fmaxf(o, 0.f);
    out[oi] = o;
}

// ---------------- Host ----------------

extern "C" void kernel_launch(void* const* d_in, const int* in_sizes, int n_in,
                              void* d_out, int out_size, void* d_ws, size_t ws_size,
                              hipStream_t stream) {
    const float* x_user    = (const float*)d_in[0];
    const float* x_problem = (const float*)d_in[1];
    const float* x_topic   = (const float*)d_in[2];
    const int* up_src = (const int*)d_in[3];
    const int* up_dst = (const int*)d_in[4];
    const int* pt_src = (const int*)d_in[5];
    const int* pt_dst = (const int*)d_in[6];
    const int* pu_src = (const int*)d_in[7];
    const int* pu_dst = (const int*)d_in[8];
    const float* W1_up_l = (const float*)d_in[9];
    const float* W1_up_r = (const float*)d_in[10];
    const float* W1_pt_l = (const float*)d_in[11];
    const float* W1_pt_r = (const float*)d_in[12];
    const float* W1_pu_l = (const float*)d_in[13];
    const float* W1_pu_r = (const float*)d_in[14];
    const float* W2_up_l = (const float*)d_in[15];
    const float* W2_up_r = (const float*)d_in[16];
    const float* W2_pt_l = (const float*)d_in[17];
    const float* W2_pt_r = (const float*)d_in[18];
    const float* W2_pu_l = (const float*)d_in[19];
    const float* W2_pu_r = (const float*)d_in[20];
    const float* b1_up = (const float*)d_in[21];
    const float* b1_pt = (const float*)d_in[22];
    const float* b1_pu = (const float*)d_in[23];
    const float* b2_up = (const float*)d_in[24];
    const float* b2_pt = (const float*)d_in[25];
    const float* b2_pu = (const float*)d_in[26];

    int n_user = in_sizes[0] / 64;
    int n_problem = in_sizes[1] / 64;
    int n_topic = in_sizes[2] / 64;
    int E_up = in_sizes[3];
    int E_pt = in_sizes[5];
    int E_pu = in_sizes[7];
    int E_tot = E_up + E_pt + E_pu;

    float* o_user = (float*)d_out;
    float* o_problem = o_user + (size_t)n_user * 64;
    float* o_topic = o_problem + (size_t)n_problem * 64;

    char* ws = (char*)d_ws;
    size_t off = 0;
    auto alloc = [&](size_t bytes) -> void* {
        void* p = ws + off;
        off += (bytes + 255) & ~(size_t)255;
        return p;
    };
    float* h_user    = (float*)alloc((size_t)n_user * 64 * 4);
    float* h_problem = (float*)alloc((size_t)n_problem * 64 * 4);
    float* h_topic   = (float*)alloc((size_t)n_topic * 64 * 4);
    // bf16 y buffers; front of this region doubles as ebuf (int per edge) during CSR build
    unsigned short* y_up = (unsigned short*)alloc((size_t)n_user * 64 * 2);
    unsigned short* y_pt = (unsigned short*)alloc((size_t)n_problem * 64 * 2);
    unsigned short* y_pu = (unsigned short*)alloc((size_t)n_problem * 64 * 2);
    int* ebuf = (int*)y_up;  // E_tot*4 = 8.3MB needed; y_up..y_pu = 11.5MB available

    auto cdiv = [](int a, int b) { return (a + b - 1) / b; };

    // buckets: relations ordered [up(dst=problem), pt(dst=topic), pu(dst=user)]
    int nb0 = cdiv(n_problem, 128), nb1 = cdiv(n_topic, 128), nb2 = cdiv(n_user, 128);
    int NB = nb0 + nb1 + nb2;

    int* gcnt  = (int*)alloc((size_t)(NB) * 4);
    int* bbase = (int*)alloc((size_t)(NB + 1) * 4);
    int* bcur  = (int*)alloc((size_t)(NB + 1) * 4);
    int* rowcat = (int*)alloc((size_t)(n_problem + n_topic + n_user + 3) * 4);
    int* ccsr  = (int*)alloc((size_t)E_tot * 4);

    BJobs B;
    B.src[0] = up_src; B.dst[0] = up_dst; B.E[0] = E_up;
    B.src[1] = pt_src; B.dst[1] = pt_dst; B.E[1] = E_pt;
    B.src[2] = pu_src; B.dst[2] = pu_dst; B.E[2] = E_pu;
    B.Eoff[0] = 0; B.Eoff[1] = E_up; B.Eoff[2] = E_up + E_pt; B.Eoff[3] = E_tot;
    B.nboff[0] = 0; B.nboff[1] = nb0; B.nboff[2] = nb0 + nb1; B.nboff[3] = NB;
    B.ndst[0] = n_problem; B.ndst[1] = n_topic; B.ndst[2] = n_user;
    B.Roff[0] = 0; B.Roff[1] = n_problem + 1; B.Roff[2] = n_problem + 1 + n_topic + 1;
    B.chunk_off[0] = 0;
    for (int r = 0; r < 3; ++r) B.chunk_off[r + 1] = B.chunk_off[r] + cdiv(B.E[r], CHUNK_E);

    const int* row_up = rowcat + B.Roff[0];
    const int* row_pt = rowcat + B.Roff[1];
    const int* row_pu = rowcat + B.Roff[2];
    const int* csr_up = ccsr + B.Eoff[0];
    const int* csr_pt = ccsr + B.Eoff[1];
    const int* csr_pu = ccsr + B.Eoff[2];

    zero_kernel<<<cdiv(NB, 256), 256, 0, stream>>>(gcnt, NB);
    bhist_kernel<<<B.chunk_off[3], BLK, 0, stream>>>(B, gcnt, NB);
    bscan_kernel<<<1, BLK, 0, stream>>>(gcnt, bbase, bcur, NB);
    bbin_kernel<<<B.chunk_off[3], BLK, 0, stream>>>(B, bcur, ebuf, NB);
    bplace_kernel<<<B.nboff[3], BLK, 0, stream>>>(B, bbase, ebuf, ccsr, rowcat);

    // ---- layer 1 ----
    {
        TJobs T;
        const float* xs[6] = {x_user, x_problem, x_problem, x_problem, x_topic, x_user};
        const float* Ws[6] = {W1_up_l, W1_pt_l, W1_pu_l, W1_up_r, W1_pt_r, W1_pu_r};
        const float* bs[6] = {nullptr, nullptr, nullptr, b1_up, b1_pt, b1_pu};
        void* ys[6] = {y_up, y_pt, y_pu, h_problem, h_topic, h_user};
        int ns[6] = {n_user, n_problem, n_problem, n_problem, n_topic, n_user};
        int ob[6] = {1, 1, 1, 0, 0, 0};
        T.boff[0] = 0;
        for (int j = 0; j < 6; ++j) {
            T.x[j] = xs[j]; T.W[j] = Ws[j]; T.b[j] = bs[j]; T.y[j] = ys[j]; T.n[j] = ns[j];
            T.obf16[j] = ob[j];
            T.boff[j + 1] = T.boff[j] + cdiv(ns[j], 128);
        }
        transform_kernel<<<T.boff[6], BLK, 0, stream>>>(T);

        GJobs G;
        const unsigned short* gy[3] = {y_pu, y_up, y_pt};
        const int* gr[3] = {row_pu, row_up, row_pt};
        const int* gc[3] = {csr_pu, csr_up, csr_pt};
        float* go[3] = {h_user, h_problem, h_topic};
        int gn[3] = {n_user, n_problem, n_topic};
        G.boff[0] = 0;
        for (int j = 0; j < 3; ++j) {
            G.y[j] = gy[j]; G.row[j] = gr[j]; G.csr[j] = gc[j]; G.out[j] = go[j]; G.n[j] = gn[j];
            G.boff[j + 1] = G.boff[j] + cdiv(gn[j], 4);
        }
        G.relu = 1;
        gather_kernel<<<G.boff[3], BLK, 0, stream>>>(G);
    }

    // ---- layer 2 ----
    {
        TJobs T;
        const float* xs[6] = {h_user, h_problem, h_problem, h_problem, h_topic, h_user};
        const float* Ws[6] = {W2_up_l, W2_pt_l, W2_pu_l, W2_up_r, W2_pt_r, W2_pu_r};
        const float* bs[6] = {nullptr, nullptr, nullptr, b2_up, b2_pt, b2_pu};
        void* ys[6] = {y_up, y_pt, y_pu, o_problem, o_topic, o_user};
        int ns[6] = {n_user, n_problem, n_problem, n_problem, n_topic, n_user};
        int ob[6] = {1, 1, 1, 0, 0, 0};
        T.boff[0] = 0;
        for (int j = 0; j < 6; ++j) {
            T.x[j] = xs[j]; T.W[j] = Ws[j]; T.b[j] = bs[j]; T.y[j] = ys[j]; T.n[j] = ns[j];
            T.obf16[j] = ob[j];
            T.boff[j + 1] = T.boff[j] + cdiv(ns[j], 128);
        }
        transform_kernel<<<T.boff[6], BLK, 0, stream>>>(T);

        GJobs G;
        const unsigned short* gy[3] = {y_pu, y_up, y_pt};
        const int* gr[3] = {row_pu, row_up, row_pt};
        const int* gc[3] = {csr_pu, csr_up, csr_pt};
        float* go[3] = {o_user, o_problem, o_topic};
        int gn[3] = {n_user, n_problem, n_topic};
        G.boff[0] = 0;
        for (int j = 0; j < 3; ++j) {
            G.y[j] = gy[j]; G.row[j] = gr[j]; G.csr[j] = gc[j]; G.out[j] = go[j]; G.n[j] = gn[j];
            G.boff[j + 1] = G.boff[j] + cdiv(gn[j], 4);
        }
        G.relu = 0;
        gather_kernel<<<G.boff[3], BLK, 0, stream>>>(G);
    }
}

// Round 10
// 218.884 us; speedup vs baseline: 1.9514x; 1.1527x over previous
//
#include <hip/hip_runtime.h>

#define BLK 256
#define SB_SHIFT 7          // 128 dst per bucket
#define NBMAX 576
#define CHUNK_E 4096
#define TPAD 68             // floats per LDS row (272B, 16B-aligned)

__device__ inline unsigned short f2bf(float f) {
    union { float f; unsigned u; } c; c.f = f;
    unsigned u = c.u + (0x7fffu + ((c.u >> 16) & 1u));   // RNE
    return (unsigned short)(u >> 16);
}
__device__ inline float bf2f(unsigned short h) {
    union { unsigned u; float f; } c; c.u = ((unsigned)h) << 16;
    return c.f;
}

// ---------------- generic zero ----------------

__global__ void zero_kernel(int* __restrict__ p, int n) {
    int i = blockIdx.x * blockDim.x + threadIdx.x;
    if (i < n) p[i] = 0;
}

// ---------------- bucketed CSR build ----------------

struct BJobs {
    const int* src[3];
    const int* dst[3];
    int E[3];
    int Eoff[4];       // concat edge offsets per relation
    int nboff[4];      // concat bucket-id offsets per relation
    int ndst[3];
    int Roff[3];       // row_ptr concat offsets per relation
    int chunk_off[4];  // chunk-block offsets per relation
};

__launch_bounds__(BLK)
__global__ void bhist_kernel(BJobs J, int* __restrict__ gcnt, int NB) {
    __shared__ int lc[NBMAX];
    int tid = threadIdx.x;
    for (int i = tid; i < NB; i += BLK) lc[i] = 0;
    __syncthreads();
    int b = blockIdx.x, r = 0;
    while (b >= J.chunk_off[r + 1]) ++r;
    int e0 = (b - J.chunk_off[r]) * CHUNK_E;
    int e1 = min(e0 + CHUNK_E, J.E[r]);
    const int* __restrict__ dst = J.dst[r];
    int base = J.nboff[r];
    for (int e = e0 + tid; e < e1; e += BLK)
        atomicAdd(&lc[base + (dst[e] >> SB_SHIFT)], 1);
    __syncthreads();
    for (int i = tid; i < NB; i += BLK)
        if (lc[i]) atomicAdd(&gcnt[i], lc[i]);
}

// Block-wide exclusive scan (256 threads, 16 items/thread/chunk).
__device__ void scan_block(const int* __restrict__ cnt, int* __restrict__ row,
                           int* __restrict__ cur, int n) {
    __shared__ int wsum[4];
    __shared__ int s_carry;
    const int ITEMS = 16;
    const int CHUNK = BLK * ITEMS;
    int lane = threadIdx.x & 63;
    int wv = threadIdx.x >> 6;
    if (threadIdx.x == 0) s_carry = 0;
    __syncthreads();
    for (int base = 0; base < n; base += CHUNK) {
        int idx0 = base + threadIdx.x * ITEMS;
        int v[ITEMS];
        int tsum = 0;
#pragma unroll
        for (int j = 0; j < ITEMS; ++j) {
            int i = idx0 + j;
            v[j] = (i < n) ? cnt[i] : 0;
            tsum += v[j];
        }
        int incl = tsum;
#pragma unroll
        for (int off = 1; off < 64; off <<= 1) {
            int t = __shfl_up(incl, off);
            if (lane >= off) incl += t;
        }
        if (lane == 63) wsum[wv] = incl;
        __syncthreads();
        int carry = s_carry;
        int woff = 0;
        for (int w = 0; w < wv; ++w) woff += wsum[w];
        int excl = carry + woff + (incl - tsum);
#pragma unroll
        for (int j = 0; j < ITEMS; ++j) {
            int i = idx0 + j;
            if (i < n) { row[i] = excl; cur[i] = excl; }
            excl += v[j];
        }
        __syncthreads();
        if (threadIdx.x == 0) s_carry = carry + wsum[0] + wsum[1] + wsum[2] + wsum[3];
        __syncthreads();
    }
    if (threadIdx.x == 0) row[n] = s_carry;
}

__global__ void bscan_kernel(const int* __restrict__ gcnt, int* __restrict__ bbase,
                             int* __restrict__ bcur, int n) {
    scan_block(gcnt, bbase, bcur, n);
}

// ebuf entry: (src << SB_SHIFT) | dst_local  (src < 2^17, dst_local < 2^7)
__launch_bounds__(BLK)
__global__ void bbin_kernel(BJobs J, int* __restrict__ bcur, int* __restrict__ ebuf, int NB) {
    __shared__ int lc[NBMAX];
    __shared__ int res[NBMAX];
    __shared__ int cur[NBMAX];
    int tid = threadIdx.x;
    for (int i = tid; i < NB; i += BLK) { lc[i] = 0; cur[i] = 0; }
    __syncthreads();
    int b = blockIdx.x, r = 0;
    while (b >= J.chunk_off[r + 1]) ++r;
    int e0 = (b - J.chunk_off[r]) * CHUNK_E;
    int e1 = min(e0 + CHUNK_E, J.E[r]);
    const int* __restrict__ src = J.src[r];
    const int* __restrict__ dst = J.dst[r];
    int base = J.nboff[r];
    for (int e = e0 + tid; e < e1; e += BLK)
        atomicAdd(&lc[base + (dst[e] >> SB_SHIFT)], 1);
    __syncthreads();
    for (int i = tid; i < NB; i += BLK)
        if (lc[i]) res[i] = atomicAdd(&bcur[i], lc[i]);
    __syncthreads();
    for (int e = e0 + tid; e < e1; e += BLK) {
        int s = src[e], d = dst[e];
        int bk = base + (d >> SB_SHIFT);
        int l = atomicAdd(&cur[bk], 1);
        ebuf[res[bk] + l] = (s << SB_SHIFT) | (d & 127);
    }
}

// One block per bucket: per-dst count, 128-wide scan, write row_ptr, place edges.
__launch_bounds__(BLK)
__global__ void bplace_kernel(BJobs J, const int* __restrict__ bbase,
                              const int* __restrict__ ebuf,
                              int* __restrict__ ccsr, int* __restrict__ rowcat) {
    __shared__ int cnt[128];
    __shared__ int off[128];
    __shared__ int cur[128];
    int tid = threadIdx.x;
    int bk = blockIdx.x, r = 0;
    while (bk >= J.nboff[r + 1]) ++r;
    int dst0 = (bk - J.nboff[r]) << SB_SHIFT;
    int nd = J.ndst[r] - dst0;
    if (nd > 128) nd = 128;
    int ebase = bbase[bk], eend = bbase[bk + 1];
    if (tid < 128) cnt[tid] = 0;
    __syncthreads();
    for (int e = ebase + tid; e < eend; e += BLK)
        atomicAdd(&cnt[ebuf[e] & 127], 1);
    __syncthreads();
    if (tid < 128) off[tid] = cnt[tid];
    __syncthreads();
    for (int st = 1; st < 128; st <<= 1) {
        int v = 0;
        if (tid < 128 && tid >= st) v = off[tid - st];
        __syncthreads();
        if (tid < 128) off[tid] += v;
        __syncthreads();
    }
    int Eo = J.Eoff[r];
    int* __restrict__ row = rowcat + J.Roff[r];
    if (tid < nd) {
        int ex = off[tid] - cnt[tid];           // exclusive within-bucket offset
        row[dst0 + tid] = ebase + ex - Eo;      // relation-relative
        cur[tid] = ex;
    }
    if (tid == 0 && dst0 + nd == J.ndst[r])
        row[J.ndst[r]] = bbase[J.nboff[r + 1]] - Eo;
    __syncthreads();
    for (int e = ebase + tid; e < eend; e += BLK) {
        int sd = ebuf[e];
        int l = atomicAdd(&cur[sd & 127], 1);
        ccsr[ebase + l] = sd >> SB_SHIFT;
    }
}

// ---------------- Dense transform: y = x @ W^T (+ b) ----------------
// GEMM register tile: block = 128 nodes x 64 h, thread = 8 nodes x 4 h.
// Output dtype per job: f32 (self-term, into out buffers) or bf16
// (neighbor-term y buffers, halves the gather's read traffic).

struct TJobs {
    const float* x[6];
    const float* W[6];
    const float* b[6];
    void* y[6];
    int n[6];
    int obf16[6];
    int boff[7];
};

__launch_bounds__(BLK)
__global__ void transform_kernel(TJobs J) {
    __shared__ float xlds[128 * TPAD];   // 34816 B
    __shared__ float wlds[64 * TPAD];    // 17408 B
    int b = blockIdx.x, j = 0;
    while (b >= J.boff[j + 1]) ++j;
    int n = J.n[j];
    int n0 = (b - J.boff[j]) * 128;
    const float4* __restrict__ x4 = (const float4*)J.x[j];
    const float4* __restrict__ W4 = (const float4*)J.W[j];
    const float* bb = J.b[j];
    int t = threadIdx.x;

    // stage x: 2048 float4, coalesced; linear LDS rows (stride TPAD)
#pragma unroll
    for (int q = 0; q < 8; ++q) {
        int idx = q * 256 + t;
        int node = idx >> 4, kq = idx & 15;
        float4 v = make_float4(0.f, 0.f, 0.f, 0.f);
        if (n0 + node < n) v = x4[(size_t)(n0 + node) * 16 + kq];
        *(float4*)&xlds[node * TPAD + kq * 4] = v;
    }
    // stage W transposed: wT[k][h]
#pragma unroll
    for (int q = 0; q < 4; ++q) {
        int idx = q * 256 + t;          // 1024 float4
        int h = idx >> 4, kq = idx & 15;
        float4 v = W4[idx];
        wlds[(kq * 4 + 0) * TPAD + h] = v.x;
        wlds[(kq * 4 + 1) * TPAD + h] = v.y;
        wlds[(kq * 4 + 2) * TPAD + h] = v.z;
        wlds[(kq * 4 + 3) * TPAD + h] = v.w;
    }
    __syncthreads();

    int tx = t & 15, ty = t >> 4;       // tx: h-quad, ty: node phase (0..15)
    float4 bias4 = make_float4(0.f, 0.f, 0.f, 0.f);
    if (bb) bias4 = *(const float4*)&bb[tx * 4];
    float acc[8][4];
#pragma unroll
    for (int i = 0; i < 8; ++i) {
        acc[i][0] = bias4.x; acc[i][1] = bias4.y;
        acc[i][2] = bias4.z; acc[i][3] = bias4.w;
    }

    for (int k4 = 0; k4 < 16; ++k4) {
        float4 wv0 = *(const float4*)&wlds[(k4 * 4 + 0) * TPAD + tx * 4];
        float4 wv1 = *(const float4*)&wlds[(k4 * 4 + 1) * TPAD + tx * 4];
        float4 wv2 = *(const float4*)&wlds[(k4 * 4 + 2) * TPAD + tx * 4];
        float4 wv3 = *(const float4*)&wlds[(k4 * 4 + 3) * TPAD + tx * 4];
#pragma unroll
        for (int i = 0; i < 8; ++i) {
            float4 xv = *(const float4*)&xlds[(ty + 16 * i) * TPAD + k4 * 4];
            acc[i][0] += xv.x * wv0.x + xv.y * wv1.x + xv.z * wv2.x + xv.w * wv3.x;
            acc[i][1] += xv.x * wv0.y + xv.y * wv1.y + xv.z * wv2.y + xv.w * wv3.y;
            acc[i][2] += xv.x * wv0.z + xv.y * wv1.z + xv.z * wv2.z + xv.w * wv3.z;
            acc[i][3] += xv.x * wv0.w + xv.y * wv1.w + xv.z * wv2.w + xv.w * wv3.w;
        }
    }

    if (J.obf16[j]) {
        unsigned short* __restrict__ yb = (unsigned short*)J.y[j];
#pragma unroll
        for (int i = 0; i < 8; ++i) {
            int node = n0 + ty + 16 * i;
            if (node < n) {
                ushort4 o;
                o.x = f2bf(acc[i][0]); o.y = f2bf(acc[i][1]);
                o.z = f2bf(acc[i][2]); o.w = f2bf(acc[i][3]);
                *(ushort4*)&yb[(size_t)node * 64 + tx * 4] = o;
            }
        }
    } else {
        float* __restrict__ y = (float*)J.y[j];
#pragma unroll
        for (int i = 0; i < 8; ++i) {
            int node = n0 + ty + 16 * i;
            if (node < n) {
                float4 o = make_float4(acc[i][0], acc[i][1], acc[i][2], acc[i][3]);
                ((float4*)y)[(size_t)node * 16 + tx] = o;
            }
        }
    }
}

// ---------------- Gather-mean + add (RMW into out) ----------------
// Wave handles one dst node. Lane = (edge subgroup, feature pair):
// packed bf16x2 loads cover 2 edges per wave-load; 8 loads in flight span
// 16 edges. csr indices for iteration k+1 prefetched before consuming
// iteration k's values (breaks the csr->y serial chain). Tail predicated
// (clamped index + masked add) -- no serial edge loop.

struct GJobs {
    const unsigned short* y[3];
    const int* row[3];
    const int* csr[3];
    float* out[3];
    int n[3];
    int boff[4];
    int relu;
};

__launch_bounds__(BLK)
__global__ void gather_kernel(GJobs J) {
    int b = blockIdx.x, j = 0;
    while (b >= J.boff[j + 1]) ++j;
    int lane = threadIdx.x & 63, wv = threadIdx.x >> 6;
    int node = (b - J.boff[j]) * 4 + wv;
    if (node >= J.n[j]) return;
    const int* __restrict__ row = J.row[j];
    const int* __restrict__ csr = J.csr[j];
    const unsigned short* __restrict__ y = J.y[j];
    float* __restrict__ out = J.out[j];

    int e0 = row[node], e1 = row[node + 1];
    int deg = e1 - e0;
    int sub = lane >> 5;       // edge subgroup 0/1
    int fp = lane & 31;        // feature pair -> features 2fp, 2fp+1

    float alo[8], ahi[8];
#pragma unroll
    for (int t = 0; t < 8; ++t) { alo[t] = 0.f; ahi[t] = 0.f; }

    if (deg > 0) {
        int idx[8];
#pragma unroll
        for (int t = 0; t < 8; ++t) {
            int e = e0 + t * 2 + sub;
            idx[t] = csr[e < e1 ? e : e1 - 1];
        }
        for (int e = e0; e < e1; e += 16) {
            unsigned v[8];
#pragma unroll
            for (int t = 0; t < 8; ++t)
                v[t] = *(const unsigned*)&y[(size_t)idx[t] * 64 + fp * 2];
            // prefetch next iteration's indices
#pragma unroll
            for (int t = 0; t < 8; ++t) {
                int en = e + 16 + t * 2 + sub;
                idx[t] = csr[en < e1 ? en : e1 - 1];
            }
#pragma unroll
            for (int t = 0; t < 8; ++t) {
                bool ok = (e + t * 2 + sub) < e1;
                float lo = bf2f((unsigned short)(v[t] & 0xffffu));
                float hi = bf2f((unsigned short)(v[t] >> 16));
                alo[t] += ok ? lo : 0.f;
                ahi[t] += ok ? hi : 0.f;
            }
        }
    }

    float sl = ((alo[0] + alo[1]) + (alo[2] + alo[3])) + ((alo[4] + alo[5]) + (alo[6] + alo[7]));
    float sh = ((ahi[0] + ahi[1]) + (ahi[2] + ahi[3])) + ((ahi[4] + ahi[5]) + (ahi[6] + ahi[7]));
    sl += __shfl_xor(sl, 32, 64);
    sh += __shfl_xor(sh, 32, 64);
    float inv = deg > 0 ? 1.f / (float)deg : 0.f;
    sl *= inv; sh *= inv;

    if (sub == 0) {
        size_t oi = (size_t)node * 64 + fp * 2;
        float2 z = *(const float2*)&out[oi];
        float2 o = make_float2(sl + z.x, sh + z.y);
        if (J.relu) { o.x = fmaxf(o.x, 0.f); o.y = fmaxf(o.y, 0.f); }
        *(float2*)&out[oi] = o;
    }
}

// ---------------- Host ----------------

extern "C" void kernel_launch(void* const* d_in, const int* in_sizes, int n_in,
                              void* d_out, int out_size, void* d_ws, size_t ws_size,
                              hipStream_t stream) {
    const float* x_user    = (const float*)d_in[0];
    const float* x_problem = (const float*)d_in[1];
    const float* x_topic   = (const float*)d_in[2];
    const int* up_src = (const int*)d_in[3];
    const int* up_dst = (const int*)d_in[4];
    const int* pt_src = (const int*)d_in[5];
    const int* pt_dst = (const int*)d_in[6];
    const int* pu_src = (const int*)d_in[7];
    const int* pu_dst = (const int*)d_in[8];
    const float* W1_up_l = (const float*)d_in[9];
    const float* W1_up_r = (const float*)d_in[10];
    const float* W1_pt_l = (const float*)d_in[11];
    const float* W1_pt_r = (const float*)d_in[12];
    const float* W1_pu_l = (const float*)d_in[13];
    const float* W1_pu_r = (const float*)d_in[14];
    const float* W2_up_l = (const float*)d_in[15];
    const float* W2_up_r = (const float*)d_in[16];
    const float* W2_pt_l = (const float*)d_in[17];
    const float* W2_pt_r = (const float*)d_in[18];
    const float* W2_pu_l = (const float*)d_in[19];
    const float* W2_pu_r = (const float*)d_in[20];
    const float* b1_up = (const float*)d_in[21];
    const float* b1_pt = (const float*)d_in[22];
    const float* b1_pu = (const float*)d_in[23];
    const float* b2_up = (const float*)d_in[24];
    const float* b2_pt = (const float*)d_in[25];
    const float* b2_pu = (const float*)d_in[26];

    int n_user = in_sizes[0] / 64;
    int n_problem = in_sizes[1] / 64;
    int n_topic = in_sizes[2] / 64;
    int E_up = in_sizes[3];
    int E_pt = in_sizes[5];
    int E_pu = in_sizes[7];
    int E_tot = E_up + E_pt + E_pu;

    float* o_user = (float*)d_out;
    float* o_problem = o_user + (size_t)n_user * 64;
    float* o_topic = o_problem + (size_t)n_problem * 64;

    char* ws = (char*)d_ws;
    size_t off = 0;
    auto alloc = [&](size_t bytes) -> void* {
        void* p = ws + off;
        off += (bytes + 255) & ~(size_t)255;
        return p;
    };
    float* h_user    = (float*)alloc((size_t)n_user * 64 * 4);
    float* h_problem = (float*)alloc((size_t)n_problem * 64 * 4);
    float* h_topic   = (float*)alloc((size_t)n_topic * 64 * 4);
    // bf16 y buffers; front of this region doubles as ebuf (int per edge) during CSR build
    unsigned short* y_up = (unsigned short*)alloc((size_t)n_user * 64 * 2);
    unsigned short* y_pt = (unsigned short*)alloc((size_t)n_problem * 64 * 2);
    unsigned short* y_pu = (unsigned short*)alloc((size_t)n_problem * 64 * 2);
    int* ebuf = (int*)y_up;  // E_tot*4 = 8.3MB needed; y_up..y_pu = 11.5MB available

    auto cdiv = [](int a, int b) { return (a + b - 1) / b; };

    // buckets: relations ordered [up(dst=problem), pt(dst=topic), pu(dst=user)]
    int nb0 = cdiv(n_problem, 128), nb1 = cdiv(n_topic, 128), nb2 = cdiv(n_user, 128);
    int NB = nb0 + nb1 + nb2;

    int* gcnt  = (int*)alloc((size_t)(NB) * 4);
    int* bbase = (int*)alloc((size_t)(NB + 1) * 4);
    int* bcur  = (int*)alloc((size_t)(NB + 1) * 4);
    int* rowcat = (int*)alloc((size_t)(n_problem + n_topic + n_user + 3) * 4);
    int* ccsr  = (int*)alloc((size_t)E_tot * 4);

    BJobs B;
    B.src[0] = up_src; B.dst[0] = up_dst; B.E[0] = E_up;
    B.src[1] = pt_src; B.dst[1] = pt_dst; B.E[1] = E_pt;
    B.src[2] = pu_src; B.dst[2] = pu_dst; B.E[2] = E_pu;
    B.Eoff[0] = 0; B.Eoff[1] = E_up; B.Eoff[2] = E_up + E_pt; B.Eoff[3] = E_tot;
    B.nboff[0] = 0; B.nboff[1] = nb0; B.nboff[2] = nb0 + nb1; B.nboff[3] = NB;
    B.ndst[0] = n_problem; B.ndst[1] = n_topic; B.ndst[2] = n_user;
    B.Roff[0] = 0; B.Roff[1] = n_problem + 1; B.Roff[2] = n_problem + 1 + n_topic + 1;
    B.chunk_off[0] = 0;
    for (int r = 0; r < 3; ++r) B.chunk_off[r + 1] = B.chunk_off[r] + cdiv(B.E[r], CHUNK_E);

    const int* row_up = rowcat + B.Roff[0];
    const int* row_pt = rowcat + B.Roff[1];
    const int* row_pu = rowcat + B.Roff[2];
    const int* csr_up = ccsr + B.Eoff[0];
    const int* csr_pt = ccsr + B.Eoff[1];
    const int* csr_pu = ccsr + B.Eoff[2];

    zero_kernel<<<cdiv(NB, 256), 256, 0, stream>>>(gcnt, NB);
    bhist_kernel<<<B.chunk_off[3], BLK, 0, stream>>>(B, gcnt, NB);
    bscan_kernel<<<1, BLK, 0, stream>>>(gcnt, bbase, bcur, NB);
    bbin_kernel<<<B.chunk_off[3], BLK, 0, stream>>>(B, bcur, ebuf, NB);
    bplace_kernel<<<B.nboff[3], BLK, 0, stream>>>(B, bbase, ebuf, ccsr, rowcat);

    // ---- layer 1 ----
    {
        TJobs T;
        const float* xs[6] = {x_user, x_problem, x_problem, x_problem, x_topic, x_user};
        const float* Ws[6] = {W1_up_l, W1_pt_l, W1_pu_l, W1_up_r, W1_pt_r, W1_pu_r};
        const float* bs[6] = {nullptr, nullptr, nullptr, b1_up, b1_pt, b1_pu};
        void* ys[6] = {y_up, y_pt, y_pu, h_problem, h_topic, h_user};
        int ns[6] = {n_user, n_problem, n_problem, n_problem, n_topic, n_user};
        int ob[6] = {1, 1, 1, 0, 0, 0};
        T.boff[0] = 0;
        for (int j = 0; j < 6; ++j) {
            T.x[j] = xs[j]; T.W[j] = Ws[j]; T.b[j] = bs[j]; T.y[j] = ys[j]; T.n[j] = ns[j];
            T.obf16[j] = ob[j];
            T.boff[j + 1] = T.boff[j] + cdiv(ns[j], 128);
        }
        transform_kernel<<<T.boff[6], BLK, 0, stream>>>(T);

        GJobs G;
        const unsigned short* gy[3] = {y_pu, y_up, y_pt};
        const int* gr[3] = {row_pu, row_up, row_pt};
        const int* gc[3] = {csr_pu, csr_up, csr_pt};
        float* go[3] = {h_user, h_problem, h_topic};
        int gn[3] = {n_user, n_problem, n_topic};
        G.boff[0] = 0;
        for (int j = 0; j < 3; ++j) {
            G.y[j] = gy[j]; G.row[j] = gr[j]; G.csr[j] = gc[j]; G.out[j] = go[j]; G.n[j] = gn[j];
            G.boff[j + 1] = G.boff[j] + cdiv(gn[j], 4);
        }
        G.relu = 1;
        gather_kernel<<<G.boff[3], BLK, 0, stream>>>(G);
    }

    // ---- layer 2 ----
    {
        TJobs T;
        const float* xs[6] = {h_user, h_problem, h_problem, h_problem, h_topic, h_user};
        const float* Ws[6] = {W2_up_l, W2_pt_l, W2_pu_l, W2_up_r, W2_pt_r, W2_pu_r};
        const float* bs[6] = {nullptr, nullptr, nullptr, b2_up, b2_pt, b2_pu};
        void* ys[6] = {y_up, y_pt, y_pu, o_problem, o_topic, o_user};
        int ns[6] = {n_user, n_problem, n_problem, n_problem, n_topic, n_user};
        int ob[6] = {1, 1, 1, 0, 0, 0};
        T.boff[0] = 0;
        for (int j = 0; j < 6; ++j) {
            T.x[j] = xs[j]; T.W[j] = Ws[j]; T.b[j] = bs[j]; T.y[j] = ys[j]; T.n[j] = ns[j];
            T.obf16[j] = ob[j];
            T.boff[j + 1] = T.boff[j] + cdiv(ns[j], 128);
        }
        transform_kernel<<<T.boff[6], BLK, 0, stream>>>(T);

        GJobs G;
        const unsigned short* gy[3] = {y_pu, y_up, y_pt};
        const int* gr[3] = {row_pu, row_up, row_pt};
        const int* gc[3] = {csr_pu, csr_up, csr_pt};
        float* go[3] = {o_user, o_problem, o_topic};
        int gn[3] = {n_user, n_problem, n_topic};
        G.boff[0] = 0;
        for (int j = 0; j < 3; ++j) {
            G.y[j] = gy[j]; G.row[j] = gr[j]; G.csr[j] = gc[j]; G.out[j] = go[j]; G.n[j] = gn[j];
            G.boff[j + 1] = G.boff[j] + cdiv(gn[j], 4);
        }
        G.relu = 0;
        gather_kernel<<<G.boff[3], BLK, 0, stream>>>(G);
    }
}

// Round 11
// 204.579 us; speedup vs baseline: 2.0878x; 1.0699x over previous
//
#include <hip/hip_runtime.h>

#define BLK 256
#define SB_SHIFT 7          // 128 dst per bucket
#define NBMAX 576
#define CHUNK_E 4096
#define TPAD 68             // floats per LDS row (272B, 16B-aligned)

typedef float f32x2 __attribute__((ext_vector_type(2)));

__device__ inline unsigned short f2bf(float f) {
    union { float f; unsigned u; } c; c.f = f;
    unsigned u = c.u + (0x7fffu + ((c.u >> 16) & 1u));   // RNE
    return (unsigned short)(u >> 16);
}

// ---------------- generic zero ----------------

__global__ void zero_kernel(int* __restrict__ p, int n) {
    int i = blockIdx.x * blockDim.x + threadIdx.x;
    if (i < n) p[i] = 0;
}

// ---------------- bucketed CSR build ----------------

struct BJobs {
    const int* src[3];
    const int* dst[3];
    int E[3];
    int Eoff[4];       // concat edge offsets per relation
    int nboff[4];      // concat bucket-id offsets per relation
    int ndst[3];
    int Roff[3];       // row_ptr concat offsets per relation
    int chunk_off[4];  // chunk-block offsets per relation
};

__launch_bounds__(BLK)
__global__ void bhist_kernel(BJobs J, int* __restrict__ gcnt, int NB) {
    __shared__ int lc[NBMAX];
    int tid = threadIdx.x;
    for (int i = tid; i < NB; i += BLK) lc[i] = 0;
    __syncthreads();
    int b = blockIdx.x, r = 0;
    while (b >= J.chunk_off[r + 1]) ++r;
    int e0 = (b - J.chunk_off[r]) * CHUNK_E;
    int e1 = min(e0 + CHUNK_E, J.E[r]);
    const int* __restrict__ dst = J.dst[r];
    int base = J.nboff[r];
    for (int e = e0 + tid; e < e1; e += BLK)
        atomicAdd(&lc[base + (dst[e] >> SB_SHIFT)], 1);
    __syncthreads();
    for (int i = tid; i < NB; i += BLK)
        if (lc[i]) atomicAdd(&gcnt[i], lc[i]);
}

// Block-wide exclusive scan (256 threads, 16 items/thread/chunk).
__device__ void scan_block(const int* __restrict__ cnt, int* __restrict__ row,
                           int* __restrict__ cur, int n) {
    __shared__ int wsum[4];
    __shared__ int s_carry;
    const int ITEMS = 16;
    const int CHUNK = BLK * ITEMS;
    int lane = threadIdx.x & 63;
    int wv = threadIdx.x >> 6;
    if (threadIdx.x == 0) s_carry = 0;
    __syncthreads();
    for (int base = 0; base < n; base += CHUNK) {
        int idx0 = base + threadIdx.x * ITEMS;
        int v[ITEMS];
        int tsum = 0;
#pragma unroll
        for (int j = 0; j < ITEMS; ++j) {
            int i = idx0 + j;
            v[j] = (i < n) ? cnt[i] : 0;
            tsum += v[j];
        }
        int incl = tsum;
#pragma unroll
        for (int off = 1; off < 64; off <<= 1) {
            int t = __shfl_up(incl, off);
            if (lane >= off) incl += t;
        }
        if (lane == 63) wsum[wv] = incl;
        __syncthreads();
        int carry = s_carry;
        int woff = 0;
        for (int w = 0; w < wv; ++w) woff += wsum[w];
        int excl = carry + woff + (incl - tsum);
#pragma unroll
        for (int j = 0; j < ITEMS; ++j) {
            int i = idx0 + j;
            if (i < n) { row[i] = excl; cur[i] = excl; }
            excl += v[j];
        }
        __syncthreads();
        if (threadIdx.x == 0) s_carry = carry + wsum[0] + wsum[1] + wsum[2] + wsum[3];
        __syncthreads();
    }
    if (threadIdx.x == 0) row[n] = s_carry;
}

__global__ void bscan_kernel(const int* __restrict__ gcnt, int* __restrict__ bbase,
                             int* __restrict__ bcur, int n) {
    scan_block(gcnt, bbase, bcur, n);
}

// ebuf entry: (src << SB_SHIFT) | dst_local  (src < 2^17, dst_local < 2^7)
__launch_bounds__(BLK)
__global__ void bbin_kernel(BJobs J, int* __restrict__ bcur, int* __restrict__ ebuf, int NB) {
    __shared__ int lc[NBMAX];
    __shared__ int res[NBMAX];
    __shared__ int cur[NBMAX];
    int tid = threadIdx.x;
    for (int i = tid; i < NB; i += BLK) { lc[i] = 0; cur[i] = 0; }
    __syncthreads();
    int b = blockIdx.x, r = 0;
    while (b >= J.chunk_off[r + 1]) ++r;
    int e0 = (b - J.chunk_off[r]) * CHUNK_E;
    int e1 = min(e0 + CHUNK_E, J.E[r]);
    const int* __restrict__ src = J.src[r];
    const int* __restrict__ dst = J.dst[r];
    int base = J.nboff[r];
    for (int e = e0 + tid; e < e1; e += BLK)
        atomicAdd(&lc[base + (dst[e] >> SB_SHIFT)], 1);
    __syncthreads();
    for (int i = tid; i < NB; i += BLK)
        if (lc[i]) res[i] = atomicAdd(&bcur[i], lc[i]);
    __syncthreads();
    for (int e = e0 + tid; e < e1; e += BLK) {
        int s = src[e], d = dst[e];
        int bk = base + (d >> SB_SHIFT);
        int l = atomicAdd(&cur[bk], 1);
        ebuf[res[bk] + l] = (s << SB_SHIFT) | (d & 127);
    }
}

// One block per bucket: per-dst count, 128-wide scan, write row_ptr, place edges.
__launch_bounds__(BLK)
__global__ void bplace_kernel(BJobs J, const int* __restrict__ bbase,
                              const int* __restrict__ ebuf,
                              int* __restrict__ ccsr, int* __restrict__ rowcat) {
    __shared__ int cnt[128];
    __shared__ int off[128];
    __shared__ int cur[128];
    int tid = threadIdx.x;
    int bk = blockIdx.x, r = 0;
    while (bk >= J.nboff[r + 1]) ++r;
    int dst0 = (bk - J.nboff[r]) << SB_SHIFT;
    int nd = J.ndst[r] - dst0;
    if (nd > 128) nd = 128;
    int ebase = bbase[bk], eend = bbase[bk + 1];
    if (tid < 128) cnt[tid] = 0;
    __syncthreads();
    for (int e = ebase + tid; e < eend; e += BLK)
        atomicAdd(&cnt[ebuf[e] & 127], 1);
    __syncthreads();
    if (tid < 128) off[tid] = cnt[tid];
    __syncthreads();
    for (int st = 1; st < 128; st <<= 1) {
        int v = 0;
        if (tid < 128 && tid >= st) v = off[tid - st];
        __syncthreads();
        if (tid < 128) off[tid] += v;
        __syncthreads();
    }
    int Eo = J.Eoff[r];
    int* __restrict__ row = rowcat + J.Roff[r];
    if (tid < nd) {
        int ex = off[tid] - cnt[tid];           // exclusive within-bucket offset
        row[dst0 + tid] = ebase + ex - Eo;      // relation-relative
        cur[tid] = ex;
    }
    if (tid == 0 && dst0 + nd == J.ndst[r])
        row[J.ndst[r]] = bbase[J.nboff[r + 1]] - Eo;
    __syncthreads();
    for (int e = ebase + tid; e < eend; e += BLK) {
        int sd = ebuf[e];
        int l = atomicAdd(&cur[sd & 127], 1);
        ccsr[ebase + l] = sd >> SB_SHIFT;
    }
}

// ---------------- Dense transform: y = x @ W^T (+ b) ----------------
// GEMM register tile: block = 128 nodes x 64 h, thread = 8 nodes x 4 h.

struct TJobs {
    const float* x[6];
    const float* W[6];
    const float* b[6];
    void* y[6];
    int n[6];
    int obf16[6];
    int boff[7];
};

__launch_bounds__(BLK)
__global__ void transform_kernel(TJobs J) {
    __shared__ float xlds[128 * TPAD];   // 34816 B
    __shared__ float wlds[64 * TPAD];    // 17408 B
    int b = blockIdx.x, j = 0;
    while (b >= J.boff[j + 1]) ++j;
    int n = J.n[j];
    int n0 = (b - J.boff[j]) * 128;
    const float4* __restrict__ x4 = (const float4*)J.x[j];
    const float4* __restrict__ W4 = (const float4*)J.W[j];
    const float* bb = J.b[j];
    int t = threadIdx.x;

#pragma unroll
    for (int q = 0; q < 8; ++q) {
        int idx = q * 256 + t;
        int node = idx >> 4, kq = idx & 15;
        float4 v = make_float4(0.f, 0.f, 0.f, 0.f);
        if (n0 + node < n) v = x4[(size_t)(n0 + node) * 16 + kq];
        *(float4*)&xlds[node * TPAD + kq * 4] = v;
    }
#pragma unroll
    for (int q = 0; q < 4; ++q) {
        int idx = q * 256 + t;          // 1024 float4
        int h = idx >> 4, kq = idx & 15;
        float4 v = W4[idx];
        wlds[(kq * 4 + 0) * TPAD + h] = v.x;
        wlds[(kq * 4 + 1) * TPAD + h] = v.y;
        wlds[(kq * 4 + 2) * TPAD + h] = v.z;
        wlds[(kq * 4 + 3) * TPAD + h] = v.w;
    }
    __syncthreads();

    int tx = t & 15, ty = t >> 4;       // tx: h-quad, ty: node phase (0..15)
    float4 bias4 = make_float4(0.f, 0.f, 0.f, 0.f);
    if (bb) bias4 = *(const float4*)&bb[tx * 4];
    float acc[8][4];
#pragma unroll
    for (int i = 0; i < 8; ++i) {
        acc[i][0] = bias4.x; acc[i][1] = bias4.y;
        acc[i][2] = bias4.z; acc[i][3] = bias4.w;
    }

    for (int k4 = 0; k4 < 16; ++k4) {
        float4 wv0 = *(const float4*)&wlds[(k4 * 4 + 0) * TPAD + tx * 4];
        float4 wv1 = *(const float4*)&wlds[(k4 * 4 + 1) * TPAD + tx * 4];
        float4 wv2 = *(const float4*)&wlds[(k4 * 4 + 2) * TPAD + tx * 4];
        float4 wv3 = *(const float4*)&wlds[(k4 * 4 + 3) * TPAD + tx * 4];
#pragma unroll
        for (int i = 0; i < 8; ++i) {
            float4 xv = *(const float4*)&xlds[(ty + 16 * i) * TPAD + k4 * 4];
            acc[i][0] += xv.x * wv0.x + xv.y * wv1.x + xv.z * wv2.x + xv.w * wv3.x;
            acc[i][1] += xv.x * wv0.y + xv.y * wv1.y + xv.z * wv2.y + xv.w * wv3.y;
            acc[i][2] += xv.x * wv0.z + xv.y * wv1.z + xv.z * wv2.z + xv.w * wv3.z;
            acc[i][3] += xv.x * wv0.w + xv.y * wv1.w + xv.z * wv2.w + xv.w * wv3.w;
        }
    }

    if (J.obf16[j]) {
        unsigned short* __restrict__ yb = (unsigned short*)J.y[j];
#pragma unroll
        for (int i = 0; i < 8; ++i) {
            int node = n0 + ty + 16 * i;
            if (node < n) {
                ushort4 o;
                o.x = f2bf(acc[i][0]); o.y = f2bf(acc[i][1]);
                o.z = f2bf(acc[i][2]); o.w = f2bf(acc[i][3]);
                *(ushort4*)&yb[(size_t)node * 64 + tx * 4] = o;
            }
        }
    } else {
        float* __restrict__ y = (float*)J.y[j];
#pragma unroll
        for (int i = 0; i < 8; ++i) {
            int node = n0 + ty + 16 * i;
            if (node < n) {
                float4 o = make_float4(acc[i][0], acc[i][1], acc[i][2], acc[i][3]);
                ((float4*)y)[(size_t)node * 16 + tx] = o;
            }
        }
    }
}

// ---------------- Gather-mean + add (RMW into out) ----------------
// Wave = one dst node. Lane = (edge subgroup, feature pair). Main loop:
// full 16-edge blocks, NO predication; bf16x2 unpack (2 VALU) + one
// v_pk_add_f32 per edge-pair; int-offset addressing (saddr loads).
// Single predicated epilogue for the <16-edge remainder.

struct GJobs {
    const unsigned short* y[3];
    const int* row[3];
    const int* csr[3];
    float* out[3];
    int n[3];
    int boff[4];
    int relu;
};

__launch_bounds__(BLK)
__global__ void gather_kernel(GJobs J) {
    int b = blockIdx.x, j = 0;
    while (b >= J.boff[j + 1]) ++j;
    int lane = threadIdx.x & 63, wv = threadIdx.x >> 6;
    int node = (b - J.boff[j]) * 4 + wv;
    if (node >= J.n[j]) return;
    const int* __restrict__ row = J.row[j];
    const int* __restrict__ csr = J.csr[j];
    const unsigned short* __restrict__ y = J.y[j];
    float* __restrict__ out = J.out[j];

    int e0 = row[node], e1 = row[node + 1];
    int deg = e1 - e0;
    int sub = lane >> 5;       // edge subgroup 0/1
    int fp = lane & 31;        // feature pair -> features 2fp, 2fp+1
    int fo = fp << 1;          // short offset within row

    f32x2 acc[8];
#pragma unroll
    for (int t = 0; t < 8; ++t) acc[t] = (f32x2)(0.f, 0.f);

    int e = e0;
    if (deg >= 16) {
        int idx[8];
#pragma unroll
        for (int t = 0; t < 8; ++t) idx[t] = csr[e + t * 2 + sub];
        for (;;) {
            unsigned v[8];
#pragma unroll
            for (int t = 0; t < 8; ++t)
                v[t] = *(const unsigned*)(y + ((idx[t] << 6) | fo));
            e += 16;
            bool more = (e + 16 <= e1);
            if (more) {
#pragma unroll
                for (int t = 0; t < 8; ++t) idx[t] = csr[e + t * 2 + sub];
            }
#pragma unroll
            for (int t = 0; t < 8; ++t) {
                f32x2 val;
                val.x = __uint_as_float(v[t] << 16);
                val.y = __uint_as_float(v[t] & 0xffff0000u);
                asm("v_pk_add_f32 %0, %1, %2" : "=v"(acc[t]) : "v"(val), "v"(acc[t]));
            }
            if (!more) break;
        }
    }
    if (e < e1) {   // remainder (<16 edges), predicated
        int idx[8];
#pragma unroll
        for (int t = 0; t < 8; ++t) {
            int ee = e + t * 2 + sub;
            idx[t] = csr[ee < e1 ? ee : e1 - 1];
        }
#pragma unroll
        for (int t = 0; t < 8; ++t) {
            unsigned v = *(const unsigned*)(y + ((idx[t] << 6) | fo));
            bool ok = (e + t * 2 + sub) < e1;
            f32x2 val;
            val.x = ok ? __uint_as_float(v << 16) : 0.f;
            val.y = ok ? __uint_as_float(v & 0xffff0000u) : 0.f;
            asm("v_pk_add_f32 %0, %1, %2" : "=v"(acc[t]) : "v"(val), "v"(acc[t]));
        }
    }

    f32x2 s4a = acc[0] + acc[1], s4b = acc[2] + acc[3];
    f32x2 s4c = acc[4] + acc[5], s4d = acc[6] + acc[7];
    f32x2 s = (s4a + s4b) + (s4c + s4d);
    float sl = s.x, sh = s.y;
    sl += __shfl_xor(sl, 32, 64);
    sh += __shfl_xor(sh, 32, 64);
    float inv = deg > 0 ? 1.f / (float)deg : 0.f;
    sl *= inv; sh *= inv;

    if (sub == 0) {
        size_t oi = (size_t)node * 64 + fo;
        float2 z = *(const float2*)&out[oi];
        float2 o = make_float2(sl + z.x, sh + z.y);
        if (J.relu) { o.x = fmaxf(o.x, 0.f); o.y = fmaxf(o.y, 0.f); }
        *(float2*)&out[oi] = o;
    }
}

// ---------------- Host ----------------

extern "C" void kernel_launch(void* const* d_in, const int* in_sizes, int n_in,
                              void* d_out, int out_size, void* d_ws, size_t ws_size,
                              hipStream_t stream) {
    const float* x_user    = (const float*)d_in[0];
    const float* x_problem = (const float*)d_in[1];
    const float* x_topic   = (const float*)d_in[2];
    const int* up_src = (const int*)d_in[3];
    const int* up_dst = (const int*)d_in[4];
    const int* pt_src = (const int*)d_in[5];
    const int* pt_dst = (const int*)d_in[6];
    const int* pu_src = (const int*)d_in[7];
    const int* pu_dst = (const int*)d_in[8];
    const float* W1_up_l = (const float*)d_in[9];
    const float* W1_up_r = (const float*)d_in[10];
    const float* W1_pt_l = (const float*)d_in[11];
    const float* W1_pt_r = (const float*)d_in[12];
    const float* W1_pu_l = (const float*)d_in[13];
    const float* W1_pu_r = (const float*)d_in[14];
    const float* W2_up_l = (const float*)d_in[15];
    const float* W2_up_r = (const float*)d_in[16];
    const float* W2_pt_l = (const float*)d_in[17];
    const float* W2_pt_r = (const float*)d_in[18];
    const float* W2_pu_l = (const float*)d_in[19];
    const float* W2_pu_r = (const float*)d_in[20];
    const float* b1_up = (const float*)d_in[21];
    const float* b1_pt = (const float*)d_in[22];
    const float* b1_pu = (const float*)d_in[23];
    const float* b2_up = (const float*)d_in[24];
    const float* b2_pt = (const float*)d_in[25];
    const float* b2_pu = (const float*)d_in[26];

    int n_user = in_sizes[0] / 64;
    int n_problem = in_sizes[1] / 64;
    int n_topic = in_sizes[2] / 64;
    int E_up = in_sizes[3];
    int E_pt = in_sizes[5];
    int E_pu = in_sizes[7];
    int E_tot = E_up + E_pt + E_pu;

    float* o_user = (float*)d_out;
    float* o_problem = o_user + (size_t)n_user * 64;
    float* o_topic = o_problem + (size_t)n_problem * 64;

    char* ws = (char*)d_ws;
    size_t off = 0;
    auto alloc = [&](size_t bytes) -> void* {
        void* p = ws + off;
        off += (bytes + 255) & ~(size_t)255;
        return p;
    };
    float* h_user    = (float*)alloc((size_t)n_user * 64 * 4);
    float* h_problem = (float*)alloc((size_t)n_problem * 64 * 4);
    float* h_topic   = (float*)alloc((size_t)n_topic * 64 * 4);
    // bf16 y buffers; front of this region doubles as ebuf (int per edge) during CSR build
    unsigned short* y_up = (unsigned short*)alloc((size_t)n_user * 64 * 2);
    unsigned short* y_pt = (unsigned short*)alloc((size_t)n_problem * 64 * 2);
    unsigned short* y_pu = (unsigned short*)alloc((size_t)n_problem * 64 * 2);
    int* ebuf = (int*)y_up;  // E_tot*4 = 8.3MB needed; y_up..y_pu = 11.5MB available

    auto cdiv = [](int a, int b) { return (a + b - 1) / b; };

    // buckets: relations ordered [up(dst=problem), pt(dst=topic), pu(dst=user)]
    int nb0 = cdiv(n_problem, 128), nb1 = cdiv(n_topic, 128), nb2 = cdiv(n_user, 128);
    int NB = nb0 + nb1 + nb2;

    int* gcnt  = (int*)alloc((size_t)(NB) * 4);
    int* bbase = (int*)alloc((size_t)(NB + 1) * 4);
    int* bcur  = (int*)alloc((size_t)(NB + 1) * 4);
    int* rowcat = (int*)alloc((size_t)(n_problem + n_topic + n_user + 3) * 4);
    int* ccsr  = (int*)alloc((size_t)E_tot * 4);

    BJobs B;
    B.src[0] = up_src; B.dst[0] = up_dst; B.E[0] = E_up;
    B.src[1] = pt_src; B.dst[1] = pt_dst; B.E[1] = E_pt;
    B.src[2] = pu_src; B.dst[2] = pu_dst; B.E[2] = E_pu;
    B.Eoff[0] = 0; B.Eoff[1] = E_up; B.Eoff[2] = E_up + E_pt; B.Eoff[3] = E_tot;
    B.nboff[0] = 0; B.nboff[1] = nb0; B.nboff[2] = nb0 + nb1; B.nboff[3] = NB;
    B.ndst[0] = n_problem; B.ndst[1] = n_topic; B.ndst[2] = n_user;
    B.Roff[0] = 0; B.Roff[1] = n_problem + 1; B.Roff[2] = n_problem + 1 + n_topic + 1;
    B.chunk_off[0] = 0;
    for (int r = 0; r < 3; ++r) B.chunk_off[r + 1] = B.chunk_off[r] + cdiv(B.E[r], CHUNK_E);

    const int* row_up = rowcat + B.Roff[0];
    const int* row_pt = rowcat + B.Roff[1];
    const int* row_pu = rowcat + B.Roff[2];
    const int* csr_up = ccsr + B.Eoff[0];
    const int* csr_pt = ccsr + B.Eoff[1];
    const int* csr_pu = ccsr + B.Eoff[2];

    zero_kernel<<<cdiv(NB, 256), 256, 0, stream>>>(gcnt, NB);
    bhist_kernel<<<B.chunk_off[3], BLK, 0, stream>>>(B, gcnt, NB);
    bscan_kernel<<<1, BLK, 0, stream>>>(gcnt, bbase, bcur, NB);
    bbin_kernel<<<B.chunk_off[3], BLK, 0, stream>>>(B, bcur, ebuf, NB);
    bplace_kernel<<<B.nboff[3], BLK, 0, stream>>>(B, bbase, ebuf, ccsr, rowcat);

    // ---- layer 1 ----
    {
        TJobs T;
        const float* xs[6] = {x_user, x_problem, x_problem, x_problem, x_topic, x_user};
        const float* Ws[6] = {W1_up_l, W1_pt_l, W1_pu_l, W1_up_r, W1_pt_r, W1_pu_r};
        const float* bs[6] = {nullptr, nullptr, nullptr, b1_up, b1_pt, b1_pu};
        void* ys[6] = {y_up, y_pt, y_pu, h_problem, h_topic, h_user};
        int ns[6] = {n_user, n_problem, n_problem, n_problem, n_topic, n_user};
        int ob[6] = {1, 1, 1, 0, 0, 0};
        T.boff[0] = 0;
        for (int j = 0; j < 6; ++j) {
            T.x[j] = xs[j]; T.W[j] = Ws[j]; T.b[j] = bs[j]; T.y[j] = ys[j]; T.n[j] = ns[j];
            T.obf16[j] = ob[j];
            T.boff[j + 1] = T.boff[j] + cdiv(ns[j], 128);
        }
        transform_kernel<<<T.boff[6], BLK, 0, stream>>>(T);

        GJobs G;
        const unsigned short* gy[3] = {y_pu, y_up, y_pt};
        const int* gr[3] = {row_pu, row_up, row_pt};
        const int* gc[3] = {csr_pu, csr_up, csr_pt};
        float* go[3] = {h_user, h_problem, h_topic};
        int gn[3] = {n_user, n_problem, n_topic};
        G.boff[0] = 0;
        for (int j = 0; j < 3; ++j) {
            G.y[j] = gy[j]; G.row[j] = gr[j]; G.csr[j] = gc[j]; G.out[j] = go[j]; G.n[j] = gn[j];
            G.boff[j + 1] = G.boff[j] + cdiv(gn[j], 4);
        }
        G.relu = 1;
        gather_kernel<<<G.boff[3], BLK, 0, stream>>>(G);
    }

    // ---- layer 2 ----
    {
        TJobs T;
        const float* xs[6] = {h_user, h_problem, h_problem, h_problem, h_topic, h_user};
        const float* Ws[6] = {W2_up_l, W2_pt_l, W2_pu_l, W2_up_r, W2_pt_r, W2_pu_r};
        const float* bs[6] = {nullptr, nullptr, nullptr, b2_up, b2_pt, b2_pu};
        void* ys[6] = {y_up, y_pt, y_pu, o_problem, o_topic, o_user};
        int ns[6] = {n_user, n_problem, n_problem, n_problem, n_topic, n_user};
        int ob[6] = {1, 1, 1, 0, 0, 0};
        T.boff[0] = 0;
        for (int j = 0; j < 6; ++j) {
            T.x[j] = xs[j]; T.W[j] = Ws[j]; T.b[j] = bs[j]; T.y[j] = ys[j]; T.n[j] = ns[j];
            T.obf16[j] = ob[j];
            T.boff[j + 1] = T.boff[j] + cdiv(ns[j], 128);
        }
        transform_kernel<<<T.boff[6], BLK, 0, stream>>>(T);

        GJobs G;
        const unsigned short* gy[3] = {y_pu, y_up, y_pt};
        const int* gr[3] = {row_pu, row_up, row_pt};
        const int* gc[3] = {csr_pu, csr_up, csr_pt};
        float* go[3] = {o_user, o_problem, o_topic};
        int gn[3] = {n_user, n_problem, n_topic};
        G.boff[0] = 0;
        for (int j = 0; j < 3; ++j) {
            G.y[j] = gy[j]; G.row[j] = gr[j]; G.csr[j] = gc[j]; G.out[j] = go[j]; G.n[j] = gn[j];
            G.boff[j + 1] = G.boff[j] + cdiv(gn[j], 4);
        }
        G.relu = 0;
        gather_kernel<<<G.boff[3], BLK, 0, stream>>>(G);
    }
}